// Round 15
// baseline (210.478 us; speedup 1.0000x reference)
//
#include <hip/hip_runtime.h>

constexpr int D_   = 256;
constexpr int H_   = 8;
constexpr int DH   = 32;
constexpr int L_   = 4;
constexpr int P_   = 4;
constexpr int DFF_ = 1024;
constexpr int B_   = 4;
constexpr int NQ_  = 900;
constexpr int NV_  = 21260;
constexpr int MQ   = B_ * NQ_;   // 3600
constexpr int MV   = B_ * NV_;   // 85040

typedef __attribute__((ext_vector_type(8))) short short8;
typedef __attribute__((ext_vector_type(4))) float f32x4;

static __device__ __forceinline__ unsigned short f2bf(float x) {
  union { float f; unsigned int u; } v;
  v.f = x;
  const unsigned int r = v.u + 0x7fffu + ((v.u >> 16) & 1u);
  return (unsigned short)(r >> 16);
}
static __device__ __forceinline__ float bf2f(unsigned short u) {
  union { unsigned int i; float f; } x;
  x.i = ((unsigned int)u) << 16;
  return x.f;
}

// ---------------------------------------------------------------------------
// Weight conversion: up to 9 segments f32 -> bf16 (optional scale).
// ---------------------------------------------------------------------------
struct CvtArgs {
  const float* src[9];
  unsigned short* dst[9];
  int n[9];
  float scl[9];
};

__global__ __launch_bounds__(256) void cvtw(CvtArgs a) {
  const int seg = blockIdx.y;
  const int n = a.n[seg];
  const float s = a.scl[seg];
  const float* __restrict__ sp = a.src[seg];
  unsigned short* __restrict__ d = a.dst[seg];
  for (int i = (blockIdx.x * 256 + threadIdx.x) * 4; i < n;
       i += gridDim.x * 256 * 4) {
    const float4 v = *reinterpret_cast<const float4*>(&sp[i]);
    d[i + 0] = f2bf(v.x * s); d[i + 1] = f2bf(v.y * s);
    d[i + 2] = f2bf(v.z * s); d[i + 3] = f2bf(v.w * s);
  }
}

// biasqkv[768]: Q part scaled by 1/sqrt(32); bfused[384] = [bo | ba]
__global__ void biasprep(const float* __restrict__ bin,
                         const float* __restrict__ bo,
                         const float* __restrict__ ba,
                         float* __restrict__ bqkv, float* __restrict__ bfu) {
  const int i = threadIdx.x;
  if (i < 768) bqkv[i] = (i < 256) ? bin[i] * 0.17677669529663687f : bin[i];
  if (i < 384) bfu[i] = (i < 256) ? bo[i] : ba[i - 256];
}

// ---------------------------------------------------------------------------
// Value-projection GEMM, K=256, BK=64 (4 K-steps -> half the barriers of the
// BK=32 variant). BM=BN=128, 4 waves, depth-1 named-reg prefetch, LDS 72KB.
// C bf16 = A(f32)[M,256] @ W(bf16)[256,256]^T + bias.
// ---------------------------------------------------------------------------
__global__ __launch_bounds__(256) void gemm_vp64(
    const float* __restrict__ A, const unsigned short* __restrict__ Wbf,
    const float* __restrict__ bias, unsigned short* __restrict__ C, int M) {
  constexpr int LDR = 72;   // 64 data + 8 pad (16B-aligned b128 accesses)
  __shared__ unsigned short As[2][128][LDR];
  __shared__ unsigned short Bs[2][128][LDR];

  const int t    = threadIdx.x;
  const int wave = t >> 6;
  const int l    = t & 63;
  const int n0   = blockIdx.x * 128;
  const int m0   = blockIdx.y * 128;
  const int wm   = (wave >> 1) * 64;
  const int wn   = (wave & 1) * 64;
  const int srow = t >> 1;
  const int sseg = (t & 1) * 32;    // col base within 64
  const int lr   = l & 15;
  const int lk   = (l >> 4) * 8;

  const int am = m0 + srow;
  const bool aok = am < M;
  const size_t arow = (size_t)am * 256;
  const size_t brow = (size_t)(n0 + srow) * 256;

  f32x4 acc[4][4];
#pragma unroll
  for (int i = 0; i < 4; ++i)
#pragma unroll
    for (int j = 0; j < 4; ++j) acc[i][j] = (f32x4)0.f;

  float  fr[32];
  short8 br_[4];

  auto LOAD = [&](int k0) {
    if (aok) {
#pragma unroll
      for (int j = 0; j < 8; ++j) {
        const float4 av =
            *reinterpret_cast<const float4*>(&A[arow + k0 + sseg + 4 * j]);
        fr[4 * j + 0] = av.x; fr[4 * j + 1] = av.y;
        fr[4 * j + 2] = av.z; fr[4 * j + 3] = av.w;
      }
    } else {
#pragma unroll
      for (int j = 0; j < 32; ++j) fr[j] = 0.f;
    }
#pragma unroll
    for (int j = 0; j < 4; ++j)
      br_[j] = *reinterpret_cast<const short8*>(&Wbf[brow + k0 + sseg + 8 * j]);
  };

  auto WRITE = [&](int cur) {
    alignas(16) unsigned short u[32];
#pragma unroll
    for (int j = 0; j < 32; ++j) u[j] = f2bf(fr[j]);
#pragma unroll
    for (int j = 0; j < 4; ++j) {
      *reinterpret_cast<short8*>(&As[cur][srow][sseg + 8 * j]) =
          *reinterpret_cast<short8*>(&u[8 * j]);
      *reinterpret_cast<short8*>(&Bs[cur][srow][sseg + 8 * j]) = br_[j];
    }
  };

  LOAD(0);
#pragma unroll
  for (int tt = 0; tt < 4; ++tt) {
    const int cur = tt & 1;
    WRITE(cur);
    if (tt + 1 < 4) LOAD((tt + 1) * 64);
    __syncthreads();

#pragma unroll
    for (int ks = 0; ks < 2; ++ks) {
      short8 af[4], bfr[4];
#pragma unroll
      for (int fi = 0; fi < 4; ++fi)
        af[fi] = *reinterpret_cast<const short8*>(
            &As[cur][wm + fi * 16 + lr][ks * 32 + lk]);
#pragma unroll
      for (int fj = 0; fj < 4; ++fj)
        bfr[fj] = *reinterpret_cast<const short8*>(
            &Bs[cur][wn + fj * 16 + lr][ks * 32 + lk]);
#pragma unroll
      for (int fi = 0; fi < 4; ++fi)
#pragma unroll
        for (int fj = 0; fj < 4; ++fj)
          acc[fi][fj] = __builtin_amdgcn_mfma_f32_16x16x32_bf16(
              af[fi], bfr[fj], acc[fi][fj], 0, 0, 0);
    }
  }

  const int orow = (l >> 4) * 4;
#pragma unroll
  for (int fi = 0; fi < 4; ++fi) {
#pragma unroll
    for (int fj = 0; fj < 4; ++fj) {
      const int n = n0 + wn + fj * 16 + lr;
      const float bn = bias[n];
#pragma unroll
      for (int i = 0; i < 4; ++i) {
        const int m = m0 + wm + fi * 16 + orow + i;
        if (m < M) C[(size_t)m * 256 + n] = f2bf(acc[fi][fj][i] + bn);
      }
    }
  }
}

// ---------------------------------------------------------------------------
// B-resident MFMA GEMM, K=256 fixed (small-M grids). BM=64, BN=128, 4 waves.
// ADD2 applies only for column blocks with n0 < add_nlim (block-uniform).
// ---------------------------------------------------------------------------
template <bool ABF, bool ADD2, bool RELU, bool OUTBF>
__global__ __launch_bounds__(256) void gemm_bres(
    const void* __restrict__ Ap, const float* __restrict__ A2,
    const unsigned short* __restrict__ Wbf, const float* __restrict__ bias,
    void* __restrict__ Cp, int M, int N, int add_nlim) {
  __shared__ unsigned short Bs[32768];        // 64 KB
  __shared__ unsigned short As[2][64][40];    // 10 KB

  const float* Af = (const float*)Ap;
  const unsigned short* Ab = (const unsigned short*)Ap;
  float* Cf = (float*)Cp;
  unsigned short* Cb = (unsigned short*)Cp;

  const int t    = threadIdx.x;
  const int wave = t >> 6;
  const int l    = t & 63;
  const int n0   = blockIdx.x * 128;
  const int m0   = blockIdx.y * 64;
  const int wm   = (wave >> 1) * 32;
  const int wcg  = (wave & 1) * 4;
  const int lr   = l & 15;
  const int lk8  = (l >> 4) * 8;
  const bool doadd = ADD2 && (n0 < add_nlim);

#pragma unroll
  for (int i = 0; i < 16; ++i) {
    const int e  = i * 256 + t;
    const int el = e & 63;
    const int cg = (e >> 6) & 7;
    const int st = e >> 9;
    const int row = n0 + cg * 16 + (el & 15);
    const int col = st * 32 + ((el >> 4) * 8);
    *reinterpret_cast<short8*>(&Bs[e * 8]) =
        *reinterpret_cast<const short8*>(&Wbf[(size_t)row * 256 + col]);
  }

  const int arow = t >> 2;
  const int acol = (t & 3) * 8;
  const int am   = m0 + arow;
  const bool aok = am < M;
  const size_t abase = (size_t)am * 256 + acol;

  float  fr[3][8];
  short8 br_[3];

  auto ALOAD = [&](int slot, int tt) {
    const int k0 = tt * 32;
    if constexpr (ABF) {
      br_[slot] = aok ? *reinterpret_cast<const short8*>(&Ab[abase + k0])
                      : (short8)(short)0;
    } else {
      if (aok) {
        const float4 a0 = *reinterpret_cast<const float4*>(&Af[abase + k0]);
        const float4 a1 = *reinterpret_cast<const float4*>(&Af[abase + k0 + 4]);
        fr[slot][0] = a0.x; fr[slot][1] = a0.y;
        fr[slot][2] = a0.z; fr[slot][3] = a0.w;
        fr[slot][4] = a1.x; fr[slot][5] = a1.y;
        fr[slot][6] = a1.z; fr[slot][7] = a1.w;
        if constexpr (ADD2) {
          if (doadd) {
            const float4 b0 = *reinterpret_cast<const float4*>(&A2[abase + k0]);
            const float4 b1 = *reinterpret_cast<const float4*>(&A2[abase + k0 + 4]);
            fr[slot][0] += b0.x; fr[slot][1] += b0.y;
            fr[slot][2] += b0.z; fr[slot][3] += b0.w;
            fr[slot][4] += b1.x; fr[slot][5] += b1.y;
            fr[slot][6] += b1.z; fr[slot][7] += b1.w;
          }
        }
      } else {
#pragma unroll
        for (int j = 0; j < 8; ++j) fr[slot][j] = 0.f;
      }
    }
  };
  auto AWRITE = [&](int slot, int tt) {
    if constexpr (ABF) {
      *reinterpret_cast<short8*>(&As[tt & 1][arow][acol]) = br_[slot];
    } else {
      alignas(16) unsigned short u[8];
#pragma unroll
      for (int j = 0; j < 8; ++j) u[j] = f2bf(fr[slot][j]);
      *reinterpret_cast<short8*>(&As[tt & 1][arow][acol]) =
          *reinterpret_cast<short8*>(&u[0]);
    }
  };

  f32x4 acc[2][4];
#pragma unroll
  for (int fi = 0; fi < 2; ++fi)
#pragma unroll
    for (int fj = 0; fj < 4; ++fj) acc[fi][fj] = (f32x4)0.f;

  ALOAD(0, 0); ALOAD(1, 1); ALOAD(2, 2);

#pragma unroll
  for (int tt = 0; tt < 8; ++tt) {
    AWRITE(tt % 3, tt);
    if (tt + 3 < 8) ALOAD(tt % 3, tt + 3);
    __syncthreads();

    short8 afr[2];
#pragma unroll
    for (int fi = 0; fi < 2; ++fi)
      afr[fi] = *reinterpret_cast<const short8*>(&As[tt & 1][wm + fi * 16 + lr][lk8]);

#pragma unroll
    for (int fj = 0; fj < 4; ++fj) {
      const short8 bfr = *reinterpret_cast<const short8*>(
          &Bs[(((tt * 8) + wcg + fj) * 64 + l) * 8]);
      acc[0][fj] = __builtin_amdgcn_mfma_f32_16x16x32_bf16(afr[0], bfr, acc[0][fj], 0, 0, 0);
      acc[1][fj] = __builtin_amdgcn_mfma_f32_16x16x32_bf16(afr[1], bfr, acc[1][fj], 0, 0, 0);
    }
  }

  const int or4 = (l >> 4) * 4;
#pragma unroll
  for (int fi = 0; fi < 2; ++fi) {
#pragma unroll
    for (int fj = 0; fj < 4; ++fj) {
      const int n = n0 + (wave & 1) * 64 + fj * 16 + lr;
      const float bn = bias[n];
#pragma unroll
      for (int i = 0; i < 4; ++i) {
        const int m = m0 + wm + fi * 16 + or4 + i;
        if (m < M) {
          float vv = acc[fi][fj][i] + bn;
          if (RELU) vv = fmaxf(vv, 0.f);
          if (OUTBF)
            Cb[(size_t)m * N + n] = f2bf(vv);
          else
            Cf[(size_t)m * N + n] = vv;
        }
      }
    }
  }
}

// ---------------------------------------------------------------------------
// ffn2 split-K: partial[z][M][256] = h1[:, z*256:+256] @ W2[:, same]^T.
// ---------------------------------------------------------------------------
__global__ __launch_bounds__(256) void gemm_ffn2(
    const unsigned short* __restrict__ Ab,
    const unsigned short* __restrict__ Wbf,
    float* __restrict__ Cpart, int M) {
  __shared__ unsigned short Bs[32768];
  __shared__ unsigned short As[2][64][40];

  const int t    = threadIdx.x;
  const int wave = t >> 6;
  const int l    = t & 63;
  const int n0   = blockIdx.x * 128;
  const int m0   = blockIdx.y * 64;
  const int kz   = blockIdx.z * 256;
  const int wm   = (wave >> 1) * 32;
  const int wcg  = (wave & 1) * 4;
  const int lr   = l & 15;
  const int lk8  = (l >> 4) * 8;

#pragma unroll
  for (int i = 0; i < 16; ++i) {
    const int e  = i * 256 + t;
    const int el = e & 63;
    const int cg = (e >> 6) & 7;
    const int st = e >> 9;
    const int row = n0 + cg * 16 + (el & 15);
    const int col = kz + st * 32 + ((el >> 4) * 8);
    *reinterpret_cast<short8*>(&Bs[e * 8]) =
        *reinterpret_cast<const short8*>(&Wbf[(size_t)row * 1024 + col]);
  }

  const int arow = t >> 2;
  const int acol = (t & 3) * 8;
  const int am   = m0 + arow;
  const bool aok = am < M;
  const size_t abase = (size_t)am * 1024 + kz + acol;

  short8 br_[3];
  auto ALOAD = [&](int slot, int tt) {
    br_[slot] = aok ? *reinterpret_cast<const short8*>(&Ab[abase + tt * 32])
                    : (short8)(short)0;
  };
  auto AWRITE = [&](int slot, int tt) {
    *reinterpret_cast<short8*>(&As[tt & 1][arow][acol]) = br_[slot];
  };

  f32x4 acc[2][4];
#pragma unroll
  for (int fi = 0; fi < 2; ++fi)
#pragma unroll
    for (int fj = 0; fj < 4; ++fj) acc[fi][fj] = (f32x4)0.f;

  ALOAD(0, 0); ALOAD(1, 1); ALOAD(2, 2);

#pragma unroll
  for (int tt = 0; tt < 8; ++tt) {
    AWRITE(tt % 3, tt);
    if (tt + 3 < 8) ALOAD(tt % 3, tt + 3);
    __syncthreads();

    short8 afr[2];
#pragma unroll
    for (int fi = 0; fi < 2; ++fi)
      afr[fi] = *reinterpret_cast<const short8*>(&As[tt & 1][wm + fi * 16 + lr][lk8]);

#pragma unroll
    for (int fj = 0; fj < 4; ++fj) {
      const short8 bfr = *reinterpret_cast<const short8*>(
          &Bs[(((tt * 8) + wcg + fj) * 64 + l) * 8]);
      acc[0][fj] = __builtin_amdgcn_mfma_f32_16x16x32_bf16(afr[0], bfr, acc[0][fj], 0, 0, 0);
      acc[1][fj] = __builtin_amdgcn_mfma_f32_16x16x32_bf16(afr[1], bfr, acc[1][fj], 0, 0, 0);
    }
  }

  float* out = &Cpart[(size_t)blockIdx.z * M * 256];
  const int or4 = (l >> 4) * 4;
#pragma unroll
  for (int fi = 0; fi < 2; ++fi) {
#pragma unroll
    for (int fj = 0; fj < 4; ++fj) {
      const int n = n0 + (wave & 1) * 64 + fj * 16 + lr;
#pragma unroll
      for (int i = 0; i < 4; ++i) {
        const int m = m0 + wm + fi * 16 + or4 + i;
        if (m < M) out[(size_t)m * 256 + n] = acc[fi][fj][i];
      }
    }
  }
}

__global__ __launch_bounds__(256) void reduce4(const float* __restrict__ part,
                                               const float* __restrict__ bias,
                                               float* __restrict__ out, int M) {
  const size_t i = ((size_t)blockIdx.x * 256 + threadIdx.x) * 4;
  const size_t tot = (size_t)M * 256;
  if (i >= tot) return;
  const int nb = (int)(i & 255);
  float4 s = *reinterpret_cast<const float4*>(&part[i]);
  const float4 p1 = *reinterpret_cast<const float4*>(&part[tot + i]);
  const float4 p2 = *reinterpret_cast<const float4*>(&part[2 * tot + i]);
  const float4 p3 = *reinterpret_cast<const float4*>(&part[3 * tot + i]);
  const float4 bb = *reinterpret_cast<const float4*>(&bias[nb]);
  s.x += p1.x + p2.x + p3.x + bb.x;
  s.y += p1.y + p2.y + p3.y + bb.y;
  s.z += p1.z + p2.z + p3.z + bb.z;
  s.w += p1.w + p2.w + p3.w + bb.w;
  *reinterpret_cast<float4*>(&out[i]) = s;
}

// ---------------------------------------------------------------------------
// Deformable sampling. 2 queries per block, paired-channel uint gathers,
// XCD-chunked block swizzle (1800 % 8 == 0 -> bijective).
// ---------------------------------------------------------------------------
__global__ __launch_bounds__(256) void deform(const float* __restrict__ refp,
                                              const float* __restrict__ offlog,
                                              const unsigned short* __restrict__ v,
                                              unsigned int* __restrict__ accb2) {
  __shared__ float aw[2][128];
  const int nwg  = gridDim.x;
  const int cpx  = nwg >> 3;
  const int bidx = (blockIdx.x % 8) * cpx + blockIdx.x / 8;
  const int t  = threadIdx.x;
  const int tq = t >> 7;
  const int tt = t & 127;
  const int bq = bidx * 2 + tq;
  const int b  = bq / NQ_;
  const int h  = tt >> 4;
  const int dd = tt & 15;

  aw[tq][tt] = offlog[(size_t)bq * 384 + 256 + tt];
  __syncthreads();
  if (t < 16) {
    const int q = t >> 3, hh = t & 7;
    float* a = &aw[q][hh * 16];
    float mx = -1e30f;
#pragma unroll
    for (int i = 0; i < 16; ++i) mx = fmaxf(mx, a[i]);
    float e[16], s = 0.f;
#pragma unroll
    for (int i = 0; i < 16; ++i) { e[i] = expf(a[i] - mx); s += e[i]; }
    const float inv = 1.f / s;
#pragma unroll
    for (int i = 0; i < 16; ++i) a[i] = e[i] * inv;
  }
  __syncthreads();

  constexpr int ST[4] = {0, 16000, 20000, 21000};
  constexpr int HL[4] = {100, 50, 25, 13};
  constexpr int WL[4] = {160, 80, 40, 20};

  float a0 = 0.f, a1 = 0.f;
#pragma unroll
  for (int l = 0; l < L_; ++l) {
    const float rx = refp[(bq * L_ + l) * 2 + 0];
    const float ry = refp[(bq * L_ + l) * 2 + 1];
    const float Wf = (float)WL[l], Hf = (float)HL[l];
    const int   Wi = WL[l], Hi = HL[l];
    const size_t vbase = (size_t)(b * NV_ + ST[l]) * D_ + h * DH + dd * 2;
#pragma unroll
    for (int p = 0; p < P_; ++p) {
      const float ox = offlog[(size_t)bq * 384 + h * 32 + l * 8 + p * 2 + 0];
      const float oy = offlog[(size_t)bq * 384 + h * 32 + l * 8 + p * 2 + 1];
      const float locx = rx + ox / Wf;
      const float locy = ry + oy / Hf;
      const float xl = locx * Wf - 0.5f;
      const float yl = locy * Hf - 0.5f;
      const float x0 = floorf(xl), y0 = floorf(yl);
      const float wx = xl - x0, wy = yl - y0;
      const int x0i = (int)x0, y0i = (int)y0;
      const float w = aw[tq][h * 16 + l * 4 + p];

      float s0 = 0.f, s1 = 0.f;
#pragma unroll
      for (int c = 0; c < 4; ++c) {
        const int xi = x0i + (c & 1);
        const int yi = y0i + (c >> 1);
        const float cw = ((c & 1) ? wx : 1.f - wx) * ((c >> 1) ? wy : 1.f - wy);
        const bool valid = (xi >= 0) && (xi < Wi) && (yi >= 0) && (yi < Hi);
        const int xc = min(max(xi, 0), Wi - 1);
        const int yc = min(max(yi, 0), Hi - 1);
        const unsigned int g2 = *reinterpret_cast<const unsigned int*>(
            &v[vbase + (size_t)(yc * Wi + xc) * D_]);
        const float g0 = bf2f((unsigned short)(g2 & 0xffffu));
        const float g1 = bf2f((unsigned short)(g2 >> 16));
        s0 += valid ? g0 * cw : 0.f;
        s1 += valid ? g1 * cw : 0.f;
      }
      a0 += w * s0;
      a1 += w * s1;
    }
  }
  const unsigned int packed =
      (unsigned int)f2bf(a0) | ((unsigned int)f2bf(a1) << 16);
  accb2[((size_t)bq * D_ + h * DH + dd * 2) >> 1] = packed;
}

// ---------------------------------------------------------------------------
// MFMA flash MHA; fused qkvh[MQ][768]. Tile prefetch (T14-lite).
// ---------------------------------------------------------------------------
constexpr int TQM  = 64;
constexpr int NQTM = (NQ_ + TQM - 1) / TQM;   // 15

__global__ __launch_bounds__(256) void mha_mfma(
    const unsigned short* __restrict__ qkvh,
    unsigned short* __restrict__ o) {
  __shared__ unsigned short Qs[64][40];
  __shared__ unsigned short Ks[64][40];
  __shared__ unsigned short Vts[32][72];
  __shared__ unsigned short Ps[64][72];

  const int bx = blockIdx.x;
  const int qt = bx % NQTM;
  const int h  = (bx / NQTM) % H_;
  const int b  = bx / (NQTM * H_);
  const int t  = threadIdx.x;
  const int wave = t >> 6;
  const int l    = t & 63;
  const int q0   = qt * TQM;
  const int wrow = wave * 16;
  const int lr   = l & 15;
  const int lkb  = (l >> 4) * 8;

  const int kr = t >> 2, kcb = (t & 3) * 8;
  const int vk = t & 63, vdb = (t >> 6) * 8;

  short8 ku, vu;
  auto LOADKV = [&](int kt) {
    const int k0 = kt * 64;
    const int nk = min(64, NQ_ - k0);
    ku = (kr < nk) ? *reinterpret_cast<const short8*>(
                         &qkvh[(size_t)(b * NQ_ + k0 + kr) * 768 + 256 + h * DH + kcb])
                   : (short8)(short)0;
    vu = (vk < nk) ? *reinterpret_cast<const short8*>(
                         &qkvh[(size_t)(b * NQ_ + k0 + vk) * 768 + 512 + h * DH + vdb])
                   : (short8)(short)0;
  };

  {
    short8 u;
    if (q0 + kr < NQ_)
      u = *reinterpret_cast<const short8*>(
          &qkvh[(size_t)(b * NQ_ + q0 + kr) * 768 + h * DH + kcb]);
    else
      u = (short8)(short)0;
    *reinterpret_cast<short8*>(&Qs[kr][kcb]) = u;
  }
  LOADKV(0);
  __syncthreads();

  const short8 qa = *reinterpret_cast<const short8*>(&Qs[wrow + lr][lkb]);

  f32x4 oacc[2];
  oacc[0] = (f32x4)0.f; oacc[1] = (f32x4)0.f;
  float m_[4] = {-1e30f, -1e30f, -1e30f, -1e30f};
  float l_[4] = {0.f, 0.f, 0.f, 0.f};

  for (int kt = 0; kt < NQTM; ++kt) {
    const int k0 = kt * 64;
    const int nk = min(64, NQ_ - k0);
    __syncthreads();

    *reinterpret_cast<short8*>(&Ks[kr][kcb]) = ku;
#pragma unroll
    for (int j = 0; j < 8; ++j) Vts[vdb + j][vk] = (unsigned short)vu[j];

    if (kt + 1 < NQTM) LOADKV(kt + 1);
    __syncthreads();

    f32x4 sacc[4];
#pragma unroll
    for (int fj = 0; fj < 4; ++fj)
      sacc[fj] = __builtin_amdgcn_mfma_f32_16x16x32_bf16(
          qa, *reinterpret_cast<const short8*>(&Ks[16 * fj + lr][lkb]),
          (f32x4)0.f, 0, 0, 0);

    bool cv[4];
#pragma unroll
    for (int fj = 0; fj < 4; ++fj) cv[fj] = (16 * fj + lr) < nk;

    float p0[4], p1[4], p2[4], p3[4], sc_[4];
#pragma unroll
    for (int i = 0; i < 4; ++i) {
      float tm = -1e30f;
      if (cv[0]) tm = fmaxf(tm, sacc[0][i]);
      if (cv[1]) tm = fmaxf(tm, sacc[1][i]);
      if (cv[2]) tm = fmaxf(tm, sacc[2][i]);
      if (cv[3]) tm = fmaxf(tm, sacc[3][i]);
      tm = fmaxf(tm, __shfl_xor(tm, 1));
      tm = fmaxf(tm, __shfl_xor(tm, 2));
      tm = fmaxf(tm, __shfl_xor(tm, 4));
      tm = fmaxf(tm, __shfl_xor(tm, 8));
      const float mn = fmaxf(m_[i], tm);
      sc_[i] = __expf(m_[i] - mn);
      m_[i] = mn;
      const float e0 = cv[0] ? __expf(sacc[0][i] - mn) : 0.f;
      const float e1 = cv[1] ? __expf(sacc[1][i] - mn) : 0.f;
      const float e2 = cv[2] ? __expf(sacc[2][i] - mn) : 0.f;
      const float e3 = cv[3] ? __expf(sacc[3][i] - mn) : 0.f;
      p0[i] = e0; p1[i] = e1; p2[i] = e2; p3[i] = e3;
      float rs = e0 + e1 + e2 + e3;
      rs += __shfl_xor(rs, 1);
      rs += __shfl_xor(rs, 2);
      rs += __shfl_xor(rs, 4);
      rs += __shfl_xor(rs, 8);
      l_[i] = l_[i] * sc_[i] + rs;
    }

#pragma unroll
    for (int i = 0; i < 4; ++i) {
      const int pr = wrow + (l >> 4) * 4 + i;
      Ps[pr][0  + lr] = f2bf(p0[i]);
      Ps[pr][16 + lr] = f2bf(p1[i]);
      Ps[pr][32 + lr] = f2bf(p2[i]);
      Ps[pr][48 + lr] = f2bf(p3[i]);
    }

    const short8 pa0 = *reinterpret_cast<const short8*>(&Ps[wrow + lr][lkb]);
    const short8 pa1 = *reinterpret_cast<const short8*>(&Ps[wrow + lr][lkb + 32]);
#pragma unroll
    for (int nt = 0; nt < 2; ++nt) {
      f32x4 c = oacc[nt];
#pragma unroll
      for (int i = 0; i < 4; ++i) c[i] *= sc_[i];
      c = __builtin_amdgcn_mfma_f32_16x16x32_bf16(
          pa0, *reinterpret_cast<const short8*>(&Vts[16 * nt + lr][lkb]), c, 0, 0, 0);
      c = __builtin_amdgcn_mfma_f32_16x16x32_bf16(
          pa1, *reinterpret_cast<const short8*>(&Vts[16 * nt + lr][lkb + 32]), c, 0, 0, 0);
      oacc[nt] = c;
    }
  }

#pragma unroll
  for (int i = 0; i < 4; ++i) {
    const int r = (l >> 4) * 4 + i;
    const int q = q0 + wrow + r;
    if (q < NQ_) {
      const float inv = 1.f / l_[i];
      o[(size_t)(b * NQ_ + q) * D_ + h * DH + 0  + lr] = f2bf(oacc[0][i] * inv);
      o[(size_t)(b * NQ_ + q) * D_ + h * DH + 16 + lr] = f2bf(oacc[1][i] * inv);
    }
  }
}

// ---------------------------------------------------------------------------
// out = LayerNorm(res + add) * g + b — one wave per row, shfl reductions.
// ---------------------------------------------------------------------------
__global__ __launch_bounds__(256) void ln4(const float* __restrict__ res,
                                           const float* __restrict__ add,
                                           const float* __restrict__ g,
                                           const float* __restrict__ bt,
                                           float* __restrict__ out) {
  const int wave = threadIdx.x >> 6, lane = threadIdx.x & 63;
  const int r = blockIdx.x * 4 + wave;
  const size_t base = (size_t)r * D_ + lane * 4;
  const float4 a = *reinterpret_cast<const float4*>(&res[base]);
  const float4 bv = *reinterpret_cast<const float4*>(&add[base]);
  float4 x;
  x.x = a.x + bv.x; x.y = a.y + bv.y; x.z = a.z + bv.z; x.w = a.w + bv.w;

  float s = x.x + x.y + x.z + x.w;
#pragma unroll
  for (int off = 1; off < 64; off <<= 1) s += __shfl_xor(s, off);
  const float mean = s * (1.f / D_);

  const float dx0 = x.x - mean, dx1 = x.y - mean, dx2 = x.z - mean,
              dx3 = x.w - mean;
  float v = dx0 * dx0 + dx1 * dx1 + dx2 * dx2 + dx3 * dx3;
#pragma unroll
  for (int off = 1; off < 64; off <<= 1) v += __shfl_xor(v, off);
  const float rstd = rsqrtf(v * (1.f / D_) + 1e-5f);

  const float4 gg = *reinterpret_cast<const float4*>(&g[lane * 4]);
  const float4 bb = *reinterpret_cast<const float4*>(&bt[lane * 4]);
  float4 o;
  o.x = dx0 * rstd * gg.x + bb.x;
  o.y = dx1 * rstd * gg.y + bb.y;
  o.z = dx2 * rstd * gg.z + bb.z;
  o.w = dx3 * rstd * gg.w + bb.w;
  *reinterpret_cast<float4*>(&out[base]) = o;
}

// ---------------------------------------------------------------------------
extern "C" void kernel_launch(void* const* d_in, const int* in_sizes, int n_in,
                              void* d_out, int out_size, void* d_ws,
                              size_t ws_size, hipStream_t stream) {
  const float* tgt   = (const float*)d_in[0];
  const float* pos   = (const float*)d_in[1];
  const float* refp  = (const float*)d_in[2];
  const float* mem   = (const float*)d_in[3];
  const float* Wv    = (const float*)d_in[4];
  const float* bv    = (const float*)d_in[5];
  const float* Wo    = (const float*)d_in[6];
  const float* bo    = (const float*)d_in[7];
  const float* Wa    = (const float*)d_in[8];
  const float* ba    = (const float*)d_in[9];
  const float* Wca   = (const float*)d_in[10];
  const float* bca   = (const float*)d_in[11];
  const float* g1    = (const float*)d_in[12];
  const float* b1    = (const float*)d_in[13];
  const float* Win   = (const float*)d_in[14];
  const float* bin   = (const float*)d_in[15];
  const float* Wsa   = (const float*)d_in[16];
  const float* bsa   = (const float*)d_in[17];
  const float* g2    = (const float*)d_in[18];
  const float* b2    = (const float*)d_in[19];
  const float* W1    = (const float*)d_in[20];
  const float* bb1   = (const float*)d_in[21];
  const float* W2    = (const float*)d_in[22];
  const float* bb2   = (const float*)d_in[23];
  const float* g3    = (const float*)d_in[24];
  const float* b3    = (const float*)d_in[25];

  char* cur = (char*)d_ws;
  auto alloc = [&](size_t bytes) {
    char* p = cur;
    cur += (bytes + 255) & ~(size_t)255;
    return (void*)p;
  };
  unsigned short* v_bf    = (unsigned short*)alloc((size_t)MV * 256 * 2);
  float*          offlog  = (float*)alloc((size_t)MQ * 384 * 4);
  unsigned short* accb_bf = (unsigned short*)alloc((size_t)MQ * 256 * 2);
  float*          tmp     = (float*)alloc((size_t)MQ * 256 * 4);
  float*          x1      = (float*)alloc((size_t)MQ * 256 * 4);
  float*          x2      = (float*)alloc((size_t)MQ * 256 * 4);
  unsigned short* qkvh_bf = (unsigned short*)alloc((size_t)MQ * 768 * 2);
  unsigned short* obuf_bf = (unsigned short*)alloc((size_t)MQ * 256 * 2);
  unsigned short* h1_bf   = (unsigned short*)alloc((size_t)MQ * 1024 * 2);
  float*          part    = (float*)alloc((size_t)4 * MQ * 256 * 4);
  unsigned short* Wv_bf   = (unsigned short*)alloc(65536 * 2);
  unsigned short* Wfu_bf  = (unsigned short*)alloc(98304 * 2);   // [Wo|Wa]
  unsigned short* Wca_bf  = (unsigned short*)alloc(65536 * 2);
  unsigned short* Win_bf  = (unsigned short*)alloc(196608 * 2);
  unsigned short* Wsa_bf  = (unsigned short*)alloc(65536 * 2);
  unsigned short* W1_bf   = (unsigned short*)alloc(262144 * 2);
  unsigned short* W2_bf   = (unsigned short*)alloc(262144 * 2);
  float*          biasqkv = (float*)alloc(768 * 4);
  float*          bfused  = (float*)alloc(384 * 4);

  const float qscale = 0.17677669529663687f;  // 1/sqrt(32)

  // convert Wv first so vp can launch immediately; rest converts while vp
  // drains the grid.
  CvtArgs ca0;
  ca0.src[0] = Wv; ca0.dst[0] = Wv_bf; ca0.n[0] = 65536; ca0.scl[0] = 1.f;
  cvtw<<<dim3(32, 1), 256, 0, stream>>>(ca0);

  const int mqb64  = (MQ + 63) / 64;    // 57
  const int mvb128 = (MV + 127) / 128;  // 665

  // value projection -> bf16 (BK=64: 4 K-steps, half the barriers)
  gemm_vp64<<<dim3(2, mvb128), 256, 0, stream>>>(mem, Wv_bf, bv, v_bf, MV);

  CvtArgs ca1;
  ca1.src[0] = Wo;          ca1.dst[0] = Wfu_bf;         ca1.n[0] = 65536;  ca1.scl[0] = 1.f;
  ca1.src[1] = Wa;          ca1.dst[1] = Wfu_bf + 65536; ca1.n[1] = 32768;  ca1.scl[1] = 1.f;
  ca1.src[2] = Wca;         ca1.dst[2] = Wca_bf;         ca1.n[2] = 65536;  ca1.scl[2] = 1.f;
  ca1.src[3] = Win;         ca1.dst[3] = Win_bf;         ca1.n[3] = 65536;  ca1.scl[3] = qscale;
  ca1.src[4] = Win + 65536; ca1.dst[4] = Win_bf + 65536; ca1.n[4] = 131072; ca1.scl[4] = 1.f;
  ca1.src[5] = Wsa;         ca1.dst[5] = Wsa_bf;         ca1.n[5] = 65536;  ca1.scl[5] = 1.f;
  ca1.src[6] = W1;          ca1.dst[6] = W1_bf;          ca1.n[6] = 262144; ca1.scl[6] = 1.f;
  ca1.src[7] = W2;          ca1.dst[7] = W2_bf;          ca1.n[7] = 262144; ca1.scl[7] = 1.f;
  cvtw<<<dim3(64, 8), 256, 0, stream>>>(ca1);
  biasprep<<<1, 768, 0, stream>>>(bin, bo, ba, biasqkv, bfused);

  // (tgt+pos) @ [Wo|Wa] -> offlog f32  (small-M: B-resident)
  gemm_bres<false, true, false, false><<<dim3(3, mqb64), 256, 0, stream>>>(
      tgt, pos, Wfu_bf, bfused, offlog, MQ, 384, 384);
  deform<<<MQ / 2, 256, 0, stream>>>(refp, offlog, v_bf,
                                     (unsigned int*)accb_bf);
  gemm_bres<true, false, false, false><<<dim3(2, mqb64), 256, 0, stream>>>(
      accb_bf, nullptr, Wca_bf, bca, tmp, MQ, 256, 0);
  ln4<<<MQ / 4, 256, 0, stream>>>(tgt, tmp, g1, b1, x1);
  // fused QKV: cols <512 use A=x1+pos (Q pre-scaled in weights/bias), V uses x1
  gemm_bres<false, true, false, true><<<dim3(6, mqb64), 256, 0, stream>>>(
      x1, pos, Win_bf, biasqkv, qkvh_bf, MQ, 768, 512);
  mha_mfma<<<B_ * H_ * NQTM, 256, 0, stream>>>(qkvh_bf, obuf_bf);
  gemm_bres<true, false, false, false><<<dim3(2, mqb64), 256, 0, stream>>>(
      obuf_bf, nullptr, Wsa_bf, bsa, tmp, MQ, 256, 0);
  ln4<<<MQ / 4, 256, 0, stream>>>(x1, tmp, g2, b2, x2);
  gemm_bres<false, false, true, true><<<dim3(8, mqb64), 256, 0, stream>>>(
      x2, nullptr, W1_bf, bb1, h1_bf, MQ, 1024, 0);
  // ffn2: split-K x4 + deterministic reduce with bias
  gemm_ffn2<<<dim3(2, mqb64, 4), 256, 0, stream>>>(h1_bf, W2_bf, part, MQ);
  reduce4<<<(MQ * 256 / 4 + 255) / 256, 256, 0, stream>>>(part, bb2, tmp, MQ);
  ln4<<<MQ / 4, 256, 0, stream>>>(x2, tmp, g3, b3, (float*)d_out);
}

// Round 16
// 192.814 us; speedup vs baseline: 1.0916x; 1.0916x over previous
//
#include <hip/hip_runtime.h>

constexpr int D_   = 256;
constexpr int H_   = 8;
constexpr int DH   = 32;
constexpr int L_   = 4;
constexpr int P_   = 4;
constexpr int DFF_ = 1024;
constexpr int B_   = 4;
constexpr int NQ_  = 900;
constexpr int NV_  = 21260;
constexpr int MQ   = B_ * NQ_;   // 3600
constexpr int MV   = B_ * NV_;   // 85040

typedef __attribute__((ext_vector_type(8))) short short8;
typedef __attribute__((ext_vector_type(4))) float f32x4;

static __device__ __forceinline__ unsigned short f2bf(float x) {
  union { float f; unsigned int u; } v;
  v.f = x;
  const unsigned int r = v.u + 0x7fffu + ((v.u >> 16) & 1u);
  return (unsigned short)(r >> 16);
}
static __device__ __forceinline__ float bf2f(unsigned short u) {
  union { unsigned int i; float f; } x;
  x.i = ((unsigned int)u) << 16;
  return x.f;
}

// ---------------------------------------------------------------------------
// Weight conversion: 9 segments f32 -> bf16 (optional scale), one launch.
// ---------------------------------------------------------------------------
struct CvtArgs {
  const float* src[9];
  unsigned short* dst[9];
  int n[9];
  float scl[9];
};

__global__ __launch_bounds__(256) void cvtw(CvtArgs a) {
  const int seg = blockIdx.y;
  const int n = a.n[seg];
  const float s = a.scl[seg];
  const float* __restrict__ sp = a.src[seg];
  unsigned short* __restrict__ d = a.dst[seg];
  for (int i = (blockIdx.x * 256 + threadIdx.x) * 4; i < n;
       i += gridDim.x * 256 * 4) {
    const float4 v = *reinterpret_cast<const float4*>(&sp[i]);
    d[i + 0] = f2bf(v.x * s); d[i + 1] = f2bf(v.y * s);
    d[i + 2] = f2bf(v.z * s); d[i + 3] = f2bf(v.w * s);
  }
}

// biasqkv[768]: Q part scaled by 1/sqrt(32); bfused[384] = [bo | ba]
__global__ void biasprep(const float* __restrict__ bin,
                         const float* __restrict__ bo,
                         const float* __restrict__ ba,
                         float* __restrict__ bqkv, float* __restrict__ bfu) {
  const int i = threadIdx.x;
  if (i < 768) bqkv[i] = (i < 256) ? bin[i] * 0.17677669529663687f : bin[i];
  if (i < 384) bfu[i] = (i < 256) ? bo[i] : ba[i - 256];
}

// ---------------------------------------------------------------------------
// Double-buffered MFMA bf16 GEMM (generic K), depth-1 prefetch — best-measured
// large-M variant (vp floor: ~57 us, FETCH = 1x A). BM=BN=128, BK=32.
// ---------------------------------------------------------------------------
template <bool ABF, bool ADD2, bool RELU, bool OUTBF>
__global__ __launch_bounds__(256) void gemm_db(
    const void* __restrict__ Ap, const float* __restrict__ A2,
    const unsigned short* __restrict__ Wbf, const float* __restrict__ bias,
    void* __restrict__ Cp, int M, int N, int K) {
  constexpr int LDR = 40;
  __shared__ unsigned short As[2][128][LDR];
  __shared__ unsigned short Bs[2][128][LDR];

  const float* Af = (const float*)Ap;
  const unsigned short* Ab = (const unsigned short*)Ap;
  float* Cf = (float*)Cp;
  unsigned short* Cb = (unsigned short*)Cp;

  const int t    = threadIdx.x;
  const int wave = t >> 6;
  const int l    = t & 63;
  const int n0   = blockIdx.x * 128;
  const int m0   = blockIdx.y * 128;
  const int wm   = (wave >> 1) * 64;
  const int wn   = (wave & 1) * 64;
  const int srow = t >> 1;
  const int sseg = (t & 1) * 16;
  const int lr   = l & 15;
  const int lk   = (l >> 4) * 8;

  const int am = m0 + srow;
  const bool aok = am < M;
  const size_t arow = (size_t)am * K;
  const size_t brow = (size_t)(n0 + srow) * K;

  f32x4 acc[4][4];
#pragma unroll
  for (int i = 0; i < 4; ++i)
#pragma unroll
    for (int j = 0; j < 4; ++j) acc[i][j] = (f32x4)0.f;

  short8 ar0, ar1, br0, br1;

  auto LOAD = [&](int k0) {
    if constexpr (ABF) {
      if (aok) {
        ar0 = *reinterpret_cast<const short8*>(&Ab[arow + k0 + sseg]);
        ar1 = *reinterpret_cast<const short8*>(&Ab[arow + k0 + sseg + 8]);
      } else {
        ar0 = (short8)(short)0; ar1 = (short8)(short)0;
      }
    } else {
      if (aok) {
        float f[16];
#pragma unroll
        for (int j = 0; j < 4; ++j) {
          const float4 av =
              *reinterpret_cast<const float4*>(&Af[arow + k0 + sseg + 4 * j]);
          f[4 * j + 0] = av.x; f[4 * j + 1] = av.y;
          f[4 * j + 2] = av.z; f[4 * j + 3] = av.w;
        }
        if constexpr (ADD2) {
#pragma unroll
          for (int j = 0; j < 4; ++j) {
            const float4 av =
                *reinterpret_cast<const float4*>(&A2[arow + k0 + sseg + 4 * j]);
            f[4 * j + 0] += av.x; f[4 * j + 1] += av.y;
            f[4 * j + 2] += av.z; f[4 * j + 3] += av.w;
          }
        }
        alignas(16) unsigned short u[16];
#pragma unroll
        for (int j = 0; j < 16; ++j) u[j] = f2bf(f[j]);
        ar0 = *reinterpret_cast<short8*>(&u[0]);
        ar1 = *reinterpret_cast<short8*>(&u[8]);
      } else {
        ar0 = (short8)(short)0; ar1 = (short8)(short)0;
      }
    }
    br0 = *reinterpret_cast<const short8*>(&Wbf[brow + k0 + sseg]);
    br1 = *reinterpret_cast<const short8*>(&Wbf[brow + k0 + sseg + 8]);
  };

  const int nt = K >> 5;
  LOAD(0);
  for (int tt = 0; tt < nt; ++tt) {
    const int cur = tt & 1;
    *reinterpret_cast<short8*>(&As[cur][srow][sseg])     = ar0;
    *reinterpret_cast<short8*>(&As[cur][srow][sseg + 8]) = ar1;
    *reinterpret_cast<short8*>(&Bs[cur][srow][sseg])     = br0;
    *reinterpret_cast<short8*>(&Bs[cur][srow][sseg + 8]) = br1;
    if (tt + 1 < nt) LOAD((tt + 1) << 5);
    __syncthreads();

    short8 af[4], bfr[4];
#pragma unroll
    for (int fi = 0; fi < 4; ++fi)
      af[fi] = *reinterpret_cast<const short8*>(&As[cur][wm + fi * 16 + lr][lk]);
#pragma unroll
    for (int fj = 0; fj < 4; ++fj)
      bfr[fj] = *reinterpret_cast<const short8*>(&Bs[cur][wn + fj * 16 + lr][lk]);

#pragma unroll
    for (int fi = 0; fi < 4; ++fi)
#pragma unroll
      for (int fj = 0; fj < 4; ++fj)
        acc[fi][fj] = __builtin_amdgcn_mfma_f32_16x16x32_bf16(
            af[fi], bfr[fj], acc[fi][fj], 0, 0, 0);
  }

  const int orow = (l >> 4) * 4;
#pragma unroll
  for (int fi = 0; fi < 4; ++fi) {
#pragma unroll
    for (int fj = 0; fj < 4; ++fj) {
      const int n = n0 + wn + fj * 16 + lr;
      const float bn = bias[n];
#pragma unroll
      for (int i = 0; i < 4; ++i) {
        const int m = m0 + wm + fi * 16 + orow + i;
        if (m < M) {
          float vv = acc[fi][fj][i] + bn;
          if (RELU) vv = fmaxf(vv, 0.f);
          if (OUTBF)
            Cb[(size_t)m * N + n] = f2bf(vv);
          else
            Cf[(size_t)m * N + n] = vv;
        }
      }
    }
  }
}

// ---------------------------------------------------------------------------
// B-resident MFMA GEMM, K=256 fixed (small-M grids). BM=64, BN=128, 4 waves.
// ADD2 applies only for column blocks with n0 < add_nlim (block-uniform).
// ---------------------------------------------------------------------------
template <bool ABF, bool ADD2, bool RELU, bool OUTBF>
__global__ __launch_bounds__(256) void gemm_bres(
    const void* __restrict__ Ap, const float* __restrict__ A2,
    const unsigned short* __restrict__ Wbf, const float* __restrict__ bias,
    void* __restrict__ Cp, int M, int N, int add_nlim) {
  __shared__ unsigned short Bs[32768];        // 64 KB
  __shared__ unsigned short As[2][64][40];    // 10 KB

  const float* Af = (const float*)Ap;
  const unsigned short* Ab = (const unsigned short*)Ap;
  float* Cf = (float*)Cp;
  unsigned short* Cb = (unsigned short*)Cp;

  const int t    = threadIdx.x;
  const int wave = t >> 6;
  const int l    = t & 63;
  const int n0   = blockIdx.x * 128;
  const int m0   = blockIdx.y * 64;
  const int wm   = (wave >> 1) * 32;
  const int wcg  = (wave & 1) * 4;
  const int lr   = l & 15;
  const int lk8  = (l >> 4) * 8;
  const bool doadd = ADD2 && (n0 < add_nlim);

#pragma unroll
  for (int i = 0; i < 16; ++i) {
    const int e  = i * 256 + t;
    const int el = e & 63;
    const int cg = (e >> 6) & 7;
    const int st = e >> 9;
    const int row = n0 + cg * 16 + (el & 15);
    const int col = st * 32 + ((el >> 4) * 8);
    *reinterpret_cast<short8*>(&Bs[e * 8]) =
        *reinterpret_cast<const short8*>(&Wbf[(size_t)row * 256 + col]);
  }

  const int arow = t >> 2;
  const int acol = (t & 3) * 8;
  const int am   = m0 + arow;
  const bool aok = am < M;
  const size_t abase = (size_t)am * 256 + acol;

  float  fr[3][8];
  short8 br_[3];

  auto ALOAD = [&](int slot, int tt) {
    const int k0 = tt * 32;
    if constexpr (ABF) {
      br_[slot] = aok ? *reinterpret_cast<const short8*>(&Ab[abase + k0])
                      : (short8)(short)0;
    } else {
      if (aok) {
        const float4 a0 = *reinterpret_cast<const float4*>(&Af[abase + k0]);
        const float4 a1 = *reinterpret_cast<const float4*>(&Af[abase + k0 + 4]);
        fr[slot][0] = a0.x; fr[slot][1] = a0.y;
        fr[slot][2] = a0.z; fr[slot][3] = a0.w;
        fr[slot][4] = a1.x; fr[slot][5] = a1.y;
        fr[slot][6] = a1.z; fr[slot][7] = a1.w;
        if constexpr (ADD2) {
          if (doadd) {
            const float4 b0 = *reinterpret_cast<const float4*>(&A2[abase + k0]);
            const float4 b1 = *reinterpret_cast<const float4*>(&A2[abase + k0 + 4]);
            fr[slot][0] += b0.x; fr[slot][1] += b0.y;
            fr[slot][2] += b0.z; fr[slot][3] += b0.w;
            fr[slot][4] += b1.x; fr[slot][5] += b1.y;
            fr[slot][6] += b1.z; fr[slot][7] += b1.w;
          }
        }
      } else {
#pragma unroll
        for (int j = 0; j < 8; ++j) fr[slot][j] = 0.f;
      }
    }
  };
  auto AWRITE = [&](int slot, int tt) {
    if constexpr (ABF) {
      *reinterpret_cast<short8*>(&As[tt & 1][arow][acol]) = br_[slot];
    } else {
      alignas(16) unsigned short u[8];
#pragma unroll
      for (int j = 0; j < 8; ++j) u[j] = f2bf(fr[slot][j]);
      *reinterpret_cast<short8*>(&As[tt & 1][arow][acol]) =
          *reinterpret_cast<short8*>(&u[0]);
    }
  };

  f32x4 acc[2][4];
#pragma unroll
  for (int fi = 0; fi < 2; ++fi)
#pragma unroll
    for (int fj = 0; fj < 4; ++fj) acc[fi][fj] = (f32x4)0.f;

  ALOAD(0, 0); ALOAD(1, 1); ALOAD(2, 2);

#pragma unroll
  for (int tt = 0; tt < 8; ++tt) {
    AWRITE(tt % 3, tt);
    if (tt + 3 < 8) ALOAD(tt % 3, tt + 3);
    __syncthreads();

    short8 afr[2];
#pragma unroll
    for (int fi = 0; fi < 2; ++fi)
      afr[fi] = *reinterpret_cast<const short8*>(&As[tt & 1][wm + fi * 16 + lr][lk8]);

#pragma unroll
    for (int fj = 0; fj < 4; ++fj) {
      const short8 bfr = *reinterpret_cast<const short8*>(
          &Bs[(((tt * 8) + wcg + fj) * 64 + l) * 8]);
      acc[0][fj] = __builtin_amdgcn_mfma_f32_16x16x32_bf16(afr[0], bfr, acc[0][fj], 0, 0, 0);
      acc[1][fj] = __builtin_amdgcn_mfma_f32_16x16x32_bf16(afr[1], bfr, acc[1][fj], 0, 0, 0);
    }
  }

  const int or4 = (l >> 4) * 4;
#pragma unroll
  for (int fi = 0; fi < 2; ++fi) {
#pragma unroll
    for (int fj = 0; fj < 4; ++fj) {
      const int n = n0 + (wave & 1) * 64 + fj * 16 + lr;
      const float bn = bias[n];
#pragma unroll
      for (int i = 0; i < 4; ++i) {
        const int m = m0 + wm + fi * 16 + or4 + i;
        if (m < M) {
          float vv = acc[fi][fj][i] + bn;
          if (RELU) vv = fmaxf(vv, 0.f);
          if (OUTBF)
            Cb[(size_t)m * N + n] = f2bf(vv);
          else
            Cf[(size_t)m * N + n] = vv;
        }
      }
    }
  }
}

// ---------------------------------------------------------------------------
// ffn2 split-K: partial[z][M][256] = h1[:, z*256:+256] @ W2[:, same]^T.
// ---------------------------------------------------------------------------
__global__ __launch_bounds__(256) void gemm_ffn2(
    const unsigned short* __restrict__ Ab,
    const unsigned short* __restrict__ Wbf,
    float* __restrict__ Cpart, int M) {
  __shared__ unsigned short Bs[32768];
  __shared__ unsigned short As[2][64][40];

  const int t    = threadIdx.x;
  const int wave = t >> 6;
  const int l    = t & 63;
  const int n0   = blockIdx.x * 128;
  const int m0   = blockIdx.y * 64;
  const int kz   = blockIdx.z * 256;
  const int wm   = (wave >> 1) * 32;
  const int wcg  = (wave & 1) * 4;
  const int lr   = l & 15;
  const int lk8  = (l >> 4) * 8;

#pragma unroll
  for (int i = 0; i < 16; ++i) {
    const int e  = i * 256 + t;
    const int el = e & 63;
    const int cg = (e >> 6) & 7;
    const int st = e >> 9;
    const int row = n0 + cg * 16 + (el & 15);
    const int col = kz + st * 32 + ((el >> 4) * 8);
    *reinterpret_cast<short8*>(&Bs[e * 8]) =
        *reinterpret_cast<const short8*>(&Wbf[(size_t)row * 1024 + col]);
  }

  const int arow = t >> 2;
  const int acol = (t & 3) * 8;
  const int am   = m0 + arow;
  const bool aok = am < M;
  const size_t abase = (size_t)am * 1024 + kz + acol;

  short8 br_[3];
  auto ALOAD = [&](int slot, int tt) {
    br_[slot] = aok ? *reinterpret_cast<const short8*>(&Ab[abase + tt * 32])
                    : (short8)(short)0;
  };
  auto AWRITE = [&](int slot, int tt) {
    *reinterpret_cast<short8*>(&As[tt & 1][arow][acol]) = br_[slot];
  };

  f32x4 acc[2][4];
#pragma unroll
  for (int fi = 0; fi < 2; ++fi)
#pragma unroll
    for (int fj = 0; fj < 4; ++fj) acc[fi][fj] = (f32x4)0.f;

  ALOAD(0, 0); ALOAD(1, 1); ALOAD(2, 2);

#pragma unroll
  for (int tt = 0; tt < 8; ++tt) {
    AWRITE(tt % 3, tt);
    if (tt + 3 < 8) ALOAD(tt % 3, tt + 3);
    __syncthreads();

    short8 afr[2];
#pragma unroll
    for (int fi = 0; fi < 2; ++fi)
      afr[fi] = *reinterpret_cast<const short8*>(&As[tt & 1][wm + fi * 16 + lr][lk8]);

#pragma unroll
    for (int fj = 0; fj < 4; ++fj) {
      const short8 bfr = *reinterpret_cast<const short8*>(
          &Bs[(((tt * 8) + wcg + fj) * 64 + l) * 8]);
      acc[0][fj] = __builtin_amdgcn_mfma_f32_16x16x32_bf16(afr[0], bfr, acc[0][fj], 0, 0, 0);
      acc[1][fj] = __builtin_amdgcn_mfma_f32_16x16x32_bf16(afr[1], bfr, acc[1][fj], 0, 0, 0);
    }
  }

  float* out = &Cpart[(size_t)blockIdx.z * M * 256];
  const int or4 = (l >> 4) * 4;
#pragma unroll
  for (int fi = 0; fi < 2; ++fi) {
#pragma unroll
    for (int fj = 0; fj < 4; ++fj) {
      const int n = n0 + (wave & 1) * 64 + fj * 16 + lr;
#pragma unroll
      for (int i = 0; i < 4; ++i) {
        const int m = m0 + wm + fi * 16 + or4 + i;
        if (m < M) out[(size_t)m * 256 + n] = acc[fi][fj][i];
      }
    }
  }
}

__global__ __launch_bounds__(256) void reduce4(const float* __restrict__ part,
                                               const float* __restrict__ bias,
                                               float* __restrict__ out, int M) {
  const size_t i = ((size_t)blockIdx.x * 256 + threadIdx.x) * 4;
  const size_t tot = (size_t)M * 256;
  if (i >= tot) return;
  const int nb = (int)(i & 255);
  float4 s = *reinterpret_cast<const float4*>(&part[i]);
  const float4 p1 = *reinterpret_cast<const float4*>(&part[tot + i]);
  const float4 p2 = *reinterpret_cast<const float4*>(&part[2 * tot + i]);
  const float4 p3 = *reinterpret_cast<const float4*>(&part[3 * tot + i]);
  const float4 bb = *reinterpret_cast<const float4*>(&bias[nb]);
  s.x += p1.x + p2.x + p3.x + bb.x;
  s.y += p1.y + p2.y + p3.y + bb.y;
  s.z += p1.z + p2.z + p3.z + bb.z;
  s.w += p1.w + p2.w + p3.w + bb.w;
  *reinterpret_cast<float4*>(&out[i]) = s;
}

// ---------------------------------------------------------------------------
// Deformable sampling. 2 queries per block, paired-channel uint gathers,
// XCD-chunked block swizzle (1800 % 8 == 0 -> bijective).
// ---------------------------------------------------------------------------
__global__ __launch_bounds__(256) void deform(const float* __restrict__ refp,
                                              const float* __restrict__ offlog,
                                              const unsigned short* __restrict__ v,
                                              unsigned int* __restrict__ accb2) {
  __shared__ float aw[2][128];
  const int nwg  = gridDim.x;
  const int cpx  = nwg >> 3;
  const int bidx = (blockIdx.x % 8) * cpx + blockIdx.x / 8;
  const int t  = threadIdx.x;
  const int tq = t >> 7;
  const int tt = t & 127;
  const int bq = bidx * 2 + tq;
  const int b  = bq / NQ_;
  const int h  = tt >> 4;
  const int dd = tt & 15;

  aw[tq][tt] = offlog[(size_t)bq * 384 + 256 + tt];
  __syncthreads();
  if (t < 16) {
    const int q = t >> 3, hh = t & 7;
    float* a = &aw[q][hh * 16];
    float mx = -1e30f;
#pragma unroll
    for (int i = 0; i < 16; ++i) mx = fmaxf(mx, a[i]);
    float e[16], s = 0.f;
#pragma unroll
    for (int i = 0; i < 16; ++i) { e[i] = expf(a[i] - mx); s += e[i]; }
    const float inv = 1.f / s;
#pragma unroll
    for (int i = 0; i < 16; ++i) a[i] = e[i] * inv;
  }
  __syncthreads();

  constexpr int ST[4] = {0, 16000, 20000, 21000};
  constexpr int HL[4] = {100, 50, 25, 13};
  constexpr int WL[4] = {160, 80, 40, 20};

  float a0 = 0.f, a1 = 0.f;
#pragma unroll
  for (int l = 0; l < L_; ++l) {
    const float rx = refp[(bq * L_ + l) * 2 + 0];
    const float ry = refp[(bq * L_ + l) * 2 + 1];
    const float Wf = (float)WL[l], Hf = (float)HL[l];
    const int   Wi = WL[l], Hi = HL[l];
    const size_t vbase = (size_t)(b * NV_ + ST[l]) * D_ + h * DH + dd * 2;
#pragma unroll
    for (int p = 0; p < P_; ++p) {
      const float ox = offlog[(size_t)bq * 384 + h * 32 + l * 8 + p * 2 + 0];
      const float oy = offlog[(size_t)bq * 384 + h * 32 + l * 8 + p * 2 + 1];
      const float locx = rx + ox / Wf;
      const float locy = ry + oy / Hf;
      const float xl = locx * Wf - 0.5f;
      const float yl = locy * Hf - 0.5f;
      const float x0 = floorf(xl), y0 = floorf(yl);
      const float wx = xl - x0, wy = yl - y0;
      const int x0i = (int)x0, y0i = (int)y0;
      const float w = aw[tq][h * 16 + l * 4 + p];

      float s0 = 0.f, s1 = 0.f;
#pragma unroll
      for (int c = 0; c < 4; ++c) {
        const int xi = x0i + (c & 1);
        const int yi = y0i + (c >> 1);
        const float cw = ((c & 1) ? wx : 1.f - wx) * ((c >> 1) ? wy : 1.f - wy);
        const bool valid = (xi >= 0) && (xi < Wi) && (yi >= 0) && (yi < Hi);
        const int xc = min(max(xi, 0), Wi - 1);
        const int yc = min(max(yi, 0), Hi - 1);
        const unsigned int g2 = *reinterpret_cast<const unsigned int*>(
            &v[vbase + (size_t)(yc * Wi + xc) * D_]);
        const float g0 = bf2f((unsigned short)(g2 & 0xffffu));
        const float g1 = bf2f((unsigned short)(g2 >> 16));
        s0 += valid ? g0 * cw : 0.f;
        s1 += valid ? g1 * cw : 0.f;
      }
      a0 += w * s0;
      a1 += w * s1;
    }
  }
  const unsigned int packed =
      (unsigned int)f2bf(a0) | ((unsigned int)f2bf(a1) << 16);
  accb2[((size_t)bq * D_ + h * DH + dd * 2) >> 1] = packed;
}

// ---------------------------------------------------------------------------
// MFMA flash MHA; fused qkvh[MQ][768]. Tile prefetch (T14-lite).
// ---------------------------------------------------------------------------
constexpr int TQM  = 64;
constexpr int NQTM = (NQ_ + TQM - 1) / TQM;   // 15

__global__ __launch_bounds__(256) void mha_mfma(
    const unsigned short* __restrict__ qkvh,
    unsigned short* __restrict__ o) {
  __shared__ unsigned short Qs[64][40];
  __shared__ unsigned short Ks[64][40];
  __shared__ unsigned short Vts[32][72];
  __shared__ unsigned short Ps[64][72];

  const int bx = blockIdx.x;
  const int qt = bx % NQTM;
  const int h  = (bx / NQTM) % H_;
  const int b  = bx / (NQTM * H_);
  const int t  = threadIdx.x;
  const int wave = t >> 6;
  const int l    = t & 63;
  const int q0   = qt * TQM;
  const int wrow = wave * 16;
  const int lr   = l & 15;
  const int lkb  = (l >> 4) * 8;

  const int kr = t >> 2, kcb = (t & 3) * 8;
  const int vk = t & 63, vdb = (t >> 6) * 8;

  short8 ku, vu;
  auto LOADKV = [&](int kt) {
    const int k0 = kt * 64;
    const int nk = min(64, NQ_ - k0);
    ku = (kr < nk) ? *reinterpret_cast<const short8*>(
                         &qkvh[(size_t)(b * NQ_ + k0 + kr) * 768 + 256 + h * DH + kcb])
                   : (short8)(short)0;
    vu = (vk < nk) ? *reinterpret_cast<const short8*>(
                         &qkvh[(size_t)(b * NQ_ + k0 + vk) * 768 + 512 + h * DH + vdb])
                   : (short8)(short)0;
  };

  {
    short8 u;
    if (q0 + kr < NQ_)
      u = *reinterpret_cast<const short8*>(
          &qkvh[(size_t)(b * NQ_ + q0 + kr) * 768 + h * DH + kcb]);
    else
      u = (short8)(short)0;
    *reinterpret_cast<short8*>(&Qs[kr][kcb]) = u;
  }
  LOADKV(0);
  __syncthreads();

  const short8 qa = *reinterpret_cast<const short8*>(&Qs[wrow + lr][lkb]);

  f32x4 oacc[2];
  oacc[0] = (f32x4)0.f; oacc[1] = (f32x4)0.f;
  float m_[4] = {-1e30f, -1e30f, -1e30f, -1e30f};
  float l_[4] = {0.f, 0.f, 0.f, 0.f};

  for (int kt = 0; kt < NQTM; ++kt) {
    const int k0 = kt * 64;
    const int nk = min(64, NQ_ - k0);
    __syncthreads();

    *reinterpret_cast<short8*>(&Ks[kr][kcb]) = ku;
#pragma unroll
    for (int j = 0; j < 8; ++j) Vts[vdb + j][vk] = (unsigned short)vu[j];

    if (kt + 1 < NQTM) LOADKV(kt + 1);
    __syncthreads();

    f32x4 sacc[4];
#pragma unroll
    for (int fj = 0; fj < 4; ++fj)
      sacc[fj] = __builtin_amdgcn_mfma_f32_16x16x32_bf16(
          qa, *reinterpret_cast<const short8*>(&Ks[16 * fj + lr][lkb]),
          (f32x4)0.f, 0, 0, 0);

    bool cv[4];
#pragma unroll
    for (int fj = 0; fj < 4; ++fj) cv[fj] = (16 * fj + lr) < nk;

    float p0[4], p1[4], p2[4], p3[4], sc_[4];
#pragma unroll
    for (int i = 0; i < 4; ++i) {
      float tm = -1e30f;
      if (cv[0]) tm = fmaxf(tm, sacc[0][i]);
      if (cv[1]) tm = fmaxf(tm, sacc[1][i]);
      if (cv[2]) tm = fmaxf(tm, sacc[2][i]);
      if (cv[3]) tm = fmaxf(tm, sacc[3][i]);
      tm = fmaxf(tm, __shfl_xor(tm, 1));
      tm = fmaxf(tm, __shfl_xor(tm, 2));
      tm = fmaxf(tm, __shfl_xor(tm, 4));
      tm = fmaxf(tm, __shfl_xor(tm, 8));
      const float mn = fmaxf(m_[i], tm);
      sc_[i] = __expf(m_[i] - mn);
      m_[i] = mn;
      const float e0 = cv[0] ? __expf(sacc[0][i] - mn) : 0.f;
      const float e1 = cv[1] ? __expf(sacc[1][i] - mn) : 0.f;
      const float e2 = cv[2] ? __expf(sacc[2][i] - mn) : 0.f;
      const float e3 = cv[3] ? __expf(sacc[3][i] - mn) : 0.f;
      p0[i] = e0; p1[i] = e1; p2[i] = e2; p3[i] = e3;
      float rs = e0 + e1 + e2 + e3;
      rs += __shfl_xor(rs, 1);
      rs += __shfl_xor(rs, 2);
      rs += __shfl_xor(rs, 4);
      rs += __shfl_xor(rs, 8);
      l_[i] = l_[i] * sc_[i] + rs;
    }

#pragma unroll
    for (int i = 0; i < 4; ++i) {
      const int pr = wrow + (l >> 4) * 4 + i;
      Ps[pr][0  + lr] = f2bf(p0[i]);
      Ps[pr][16 + lr] = f2bf(p1[i]);
      Ps[pr][32 + lr] = f2bf(p2[i]);
      Ps[pr][48 + lr] = f2bf(p3[i]);
    }

    const short8 pa0 = *reinterpret_cast<const short8*>(&Ps[wrow + lr][lkb]);
    const short8 pa1 = *reinterpret_cast<const short8*>(&Ps[wrow + lr][lkb + 32]);
#pragma unroll
    for (int nt = 0; nt < 2; ++nt) {
      f32x4 c = oacc[nt];
#pragma unroll
      for (int i = 0; i < 4; ++i) c[i] *= sc_[i];
      c = __builtin_amdgcn_mfma_f32_16x16x32_bf16(
          pa0, *reinterpret_cast<const short8*>(&Vts[16 * nt + lr][lkb]), c, 0, 0, 0);
      c = __builtin_amdgcn_mfma_f32_16x16x32_bf16(
          pa1, *reinterpret_cast<const short8*>(&Vts[16 * nt + lr][lkb + 32]), c, 0, 0, 0);
      oacc[nt] = c;
    }
  }

#pragma unroll
  for (int i = 0; i < 4; ++i) {
    const int r = (l >> 4) * 4 + i;
    const int q = q0 + wrow + r;
    if (q < NQ_) {
      const float inv = 1.f / l_[i];
      o[(size_t)(b * NQ_ + q) * D_ + h * DH + 0  + lr] = f2bf(oacc[0][i] * inv);
      o[(size_t)(b * NQ_ + q) * D_ + h * DH + 16 + lr] = f2bf(oacc[1][i] * inv);
    }
  }
}

// ---------------------------------------------------------------------------
// out = LayerNorm(res + add) * g + b — one wave per row, shfl reductions.
// ---------------------------------------------------------------------------
__global__ __launch_bounds__(256) void ln4(const float* __restrict__ res,
                                           const float* __restrict__ add,
                                           const float* __restrict__ g,
                                           const float* __restrict__ bt,
                                           float* __restrict__ out) {
  const int wave = threadIdx.x >> 6, lane = threadIdx.x & 63;
  const int r = blockIdx.x * 4 + wave;
  const size_t base = (size_t)r * D_ + lane * 4;
  const float4 a = *reinterpret_cast<const float4*>(&res[base]);
  const float4 bv = *reinterpret_cast<const float4*>(&add[base]);
  float4 x;
  x.x = a.x + bv.x; x.y = a.y + bv.y; x.z = a.z + bv.z; x.w = a.w + bv.w;

  float s = x.x + x.y + x.z + x.w;
#pragma unroll
  for (int off = 1; off < 64; off <<= 1) s += __shfl_xor(s, off);
  const float mean = s * (1.f / D_);

  const float dx0 = x.x - mean, dx1 = x.y - mean, dx2 = x.z - mean,
              dx3 = x.w - mean;
  float v = dx0 * dx0 + dx1 * dx1 + dx2 * dx2 + dx3 * dx3;
#pragma unroll
  for (int off = 1; off < 64; off <<= 1) v += __shfl_xor(v, off);
  const float rstd = rsqrtf(v * (1.f / D_) + 1e-5f);

  const float4 gg = *reinterpret_cast<const float4*>(&g[lane * 4]);
  const float4 bb = *reinterpret_cast<const float4*>(&bt[lane * 4]);
  float4 o;
  o.x = dx0 * rstd * gg.x + bb.x;
  o.y = dx1 * rstd * gg.y + bb.y;
  o.z = dx2 * rstd * gg.z + bb.z;
  o.w = dx3 * rstd * gg.w + bb.w;
  *reinterpret_cast<float4*>(&out[base]) = o;
}

// ---------------------------------------------------------------------------
extern "C" void kernel_launch(void* const* d_in, const int* in_sizes, int n_in,
                              void* d_out, int out_size, void* d_ws,
                              size_t ws_size, hipStream_t stream) {
  const float* tgt   = (const float*)d_in[0];
  const float* pos   = (const float*)d_in[1];
  const float* refp  = (const float*)d_in[2];
  const float* mem   = (const float*)d_in[3];
  const float* Wv    = (const float*)d_in[4];
  const float* bv    = (const float*)d_in[5];
  const float* Wo    = (const float*)d_in[6];
  const float* bo    = (const float*)d_in[7];
  const float* Wa    = (const float*)d_in[8];
  const float* ba    = (const float*)d_in[9];
  const float* Wca   = (const float*)d_in[10];
  const float* bca   = (const float*)d_in[11];
  const float* g1    = (const float*)d_in[12];
  const float* b1    = (const float*)d_in[13];
  const float* Win   = (const float*)d_in[14];
  const float* bin   = (const float*)d_in[15];
  const float* Wsa   = (const float*)d_in[16];
  const float* bsa   = (const float*)d_in[17];
  const float* g2    = (const float*)d_in[18];
  const float* b2    = (const float*)d_in[19];
  const float* W1    = (const float*)d_in[20];
  const float* bb1   = (const float*)d_in[21];
  const float* W2    = (const float*)d_in[22];
  const float* bb2   = (const float*)d_in[23];
  const float* g3    = (const float*)d_in[24];
  const float* b3    = (const float*)d_in[25];

  char* cur = (char*)d_ws;
  auto alloc = [&](size_t bytes) {
    char* p = cur;
    cur += (bytes + 255) & ~(size_t)255;
    return (void*)p;
  };
  unsigned short* v_bf    = (unsigned short*)alloc((size_t)MV * 256 * 2);
  float*          offlog  = (float*)alloc((size_t)MQ * 384 * 4);
  unsigned short* accb_bf = (unsigned short*)alloc((size_t)MQ * 256 * 2);
  float*          tmp     = (float*)alloc((size_t)MQ * 256 * 4);
  float*          x1      = (float*)alloc((size_t)MQ * 256 * 4);
  float*          x2      = (float*)alloc((size_t)MQ * 256 * 4);
  unsigned short* qkvh_bf = (unsigned short*)alloc((size_t)MQ * 768 * 2);
  unsigned short* obuf_bf = (unsigned short*)alloc((size_t)MQ * 256 * 2);
  unsigned short* h1_bf   = (unsigned short*)alloc((size_t)MQ * 1024 * 2);
  float*          part    = (float*)alloc((size_t)4 * MQ * 256 * 4);
  unsigned short* Wv_bf   = (unsigned short*)alloc(65536 * 2);
  unsigned short* Wfu_bf  = (unsigned short*)alloc(98304 * 2);   // [Wo|Wa]
  unsigned short* Wca_bf  = (unsigned short*)alloc(65536 * 2);
  unsigned short* Win_bf  = (unsigned short*)alloc(196608 * 2);
  unsigned short* Wsa_bf  = (unsigned short*)alloc(65536 * 2);
  unsigned short* W1_bf   = (unsigned short*)alloc(262144 * 2);
  unsigned short* W2_bf   = (unsigned short*)alloc(262144 * 2);
  float*          biasqkv = (float*)alloc(768 * 4);
  float*          bfused  = (float*)alloc(384 * 4);

  const float qscale = 0.17677669529663687f;  // 1/sqrt(32)

  CvtArgs ca;
  ca.src[0] = Wv;            ca.dst[0] = Wv_bf;          ca.n[0] = 65536;  ca.scl[0] = 1.f;
  ca.src[1] = Wo;            ca.dst[1] = Wfu_bf;         ca.n[1] = 65536;  ca.scl[1] = 1.f;
  ca.src[2] = Wa;            ca.dst[2] = Wfu_bf + 65536; ca.n[2] = 32768;  ca.scl[2] = 1.f;
  ca.src[3] = Wca;           ca.dst[3] = Wca_bf;         ca.n[3] = 65536;  ca.scl[3] = 1.f;
  ca.src[4] = Win;           ca.dst[4] = Win_bf;         ca.n[4] = 65536;  ca.scl[4] = qscale;
  ca.src[5] = Win + 65536;   ca.dst[5] = Win_bf + 65536; ca.n[5] = 131072; ca.scl[5] = 1.f;
  ca.src[6] = Wsa;           ca.dst[6] = Wsa_bf;         ca.n[6] = 65536;  ca.scl[6] = 1.f;
  ca.src[7] = W1;            ca.dst[7] = W1_bf;          ca.n[7] = 262144; ca.scl[7] = 1.f;
  ca.src[8] = W2;            ca.dst[8] = W2_bf;          ca.n[8] = 262144; ca.scl[8] = 1.f;
  cvtw<<<dim3(64, 9), 256, 0, stream>>>(ca);
  biasprep<<<1, 768, 0, stream>>>(bin, bo, ba, biasqkv, bfused);

  const int mqb64  = (MQ + 63) / 64;    // 57
  const int mvb128 = (MV + 127) / 128;  // 665

  // value projection -> bf16 (best-measured: depth-1 double-buffer 128x128)
  gemm_db<false, false, false, true><<<dim3(2, mvb128), 256, 0, stream>>>(
      mem, nullptr, Wv_bf, bv, v_bf, MV, 256, 256);
  // (tgt+pos) @ [Wo|Wa] -> offlog f32  (small-M: B-resident)
  gemm_bres<false, true, false, false><<<dim3(3, mqb64), 256, 0, stream>>>(
      tgt, pos, Wfu_bf, bfused, offlog, MQ, 384, 384);
  deform<<<MQ / 2, 256, 0, stream>>>(refp, offlog, v_bf,
                                     (unsigned int*)accb_bf);
  gemm_bres<true, false, false, false><<<dim3(2, mqb64), 256, 0, stream>>>(
      accb_bf, nullptr, Wca_bf, bca, tmp, MQ, 256, 0);
  ln4<<<MQ / 4, 256, 0, stream>>>(tgt, tmp, g1, b1, x1);
  // fused QKV: cols <512 use A=x1+pos (Q pre-scaled in weights/bias), V uses x1
  gemm_bres<false, true, false, true><<<dim3(6, mqb64), 256, 0, stream>>>(
      x1, pos, Win_bf, biasqkv, qkvh_bf, MQ, 768, 512);
  mha_mfma<<<B_ * H_ * NQTM, 256, 0, stream>>>(qkvh_bf, obuf_bf);
  gemm_bres<true, false, false, false><<<dim3(2, mqb64), 256, 0, stream>>>(
      obuf_bf, nullptr, Wsa_bf, bsa, tmp, MQ, 256, 0);
  ln4<<<MQ / 4, 256, 0, stream>>>(x1, tmp, g2, b2, x2);
  gemm_bres<false, false, true, true><<<dim3(8, mqb64), 256, 0, stream>>>(
      x2, nullptr, W1_bf, bb1, h1_bf, MQ, 1024, 0);
  // ffn2: split-K x4 + deterministic reduce with bias
  gemm_ffn2<<<dim3(2, mqb64, 4), 256, 0, stream>>>(h1_bf, W2_bf, part, MQ);
  reduce4<<<(MQ * 256 / 4 + 255) / 256, 256, 0, stream>>>(part, bb2, tmp, MQ);
  ln4<<<MQ / 4, 256, 0, stream>>>(x2, tmp, g3, b3, (float*)d_out);
}

// Round 17
// 190.941 us; speedup vs baseline: 1.1023x; 1.0098x over previous
//
#include <hip/hip_runtime.h>

constexpr int D_   = 256;
constexpr int H_   = 8;
constexpr int DH   = 32;
constexpr int L_   = 4;
constexpr int P_   = 4;
constexpr int DFF_ = 1024;
constexpr int B_   = 4;
constexpr int NQ_  = 900;
constexpr int NV_  = 21260;
constexpr int MQ   = B_ * NQ_;   // 3600
constexpr int MV   = B_ * NV_;   // 85040

typedef __attribute__((ext_vector_type(8))) short short8;
typedef __attribute__((ext_vector_type(4))) float f32x4;

static __device__ __forceinline__ unsigned short f2bf(float x) {
  union { float f; unsigned int u; } v;
  v.f = x;
  const unsigned int r = v.u + 0x7fffu + ((v.u >> 16) & 1u);
  return (unsigned short)(r >> 16);
}
static __device__ __forceinline__ float bf2f(unsigned short u) {
  union { unsigned int i; float f; } x;
  x.i = ((unsigned int)u) << 16;
  return x.f;
}

// ---------------------------------------------------------------------------
// Weight conversion: 9 segments f32 -> bf16 (optional scale), one launch.
// ---------------------------------------------------------------------------
struct CvtArgs {
  const float* src[9];
  unsigned short* dst[9];
  int n[9];
  float scl[9];
};

__global__ __launch_bounds__(256) void cvtw(CvtArgs a) {
  const int seg = blockIdx.y;
  const int n = a.n[seg];
  const float s = a.scl[seg];
  const float* __restrict__ sp = a.src[seg];
  unsigned short* __restrict__ d = a.dst[seg];
  for (int i = (blockIdx.x * 256 + threadIdx.x) * 4; i < n;
       i += gridDim.x * 256 * 4) {
    const float4 v = *reinterpret_cast<const float4*>(&sp[i]);
    d[i + 0] = f2bf(v.x * s); d[i + 1] = f2bf(v.y * s);
    d[i + 2] = f2bf(v.z * s); d[i + 3] = f2bf(v.w * s);
  }
}

// biasqkv[768]: Q part scaled by 1/sqrt(32); bfused[384] = [bo | ba]
__global__ void biasprep(const float* __restrict__ bin,
                         const float* __restrict__ bo,
                         const float* __restrict__ ba,
                         float* __restrict__ bqkv, float* __restrict__ bfu) {
  const int i = threadIdx.x;
  if (i < 768) bqkv[i] = (i < 256) ? bin[i] * 0.17677669529663687f : bin[i];
  if (i < 384) bfu[i] = (i < 256) ? bo[i] : ba[i - 256];
}

// ---------------------------------------------------------------------------
// Double-buffered MFMA bf16 GEMM (generic K), depth-1 prefetch — best-measured
// large-M variant (vp floor: ~57 us, FETCH = 1x A). BM=BN=128, BK=32.
// ---------------------------------------------------------------------------
template <bool ABF, bool ADD2, bool RELU, bool OUTBF>
__global__ __launch_bounds__(256) void gemm_db(
    const void* __restrict__ Ap, const float* __restrict__ A2,
    const unsigned short* __restrict__ Wbf, const float* __restrict__ bias,
    void* __restrict__ Cp, int M, int N, int K) {
  constexpr int LDR = 40;
  __shared__ unsigned short As[2][128][LDR];
  __shared__ unsigned short Bs[2][128][LDR];

  const float* Af = (const float*)Ap;
  const unsigned short* Ab = (const unsigned short*)Ap;
  float* Cf = (float*)Cp;
  unsigned short* Cb = (unsigned short*)Cp;

  const int t    = threadIdx.x;
  const int wave = t >> 6;
  const int l    = t & 63;
  const int n0   = blockIdx.x * 128;
  const int m0   = blockIdx.y * 128;
  const int wm   = (wave >> 1) * 64;
  const int wn   = (wave & 1) * 64;
  const int srow = t >> 1;
  const int sseg = (t & 1) * 16;
  const int lr   = l & 15;
  const int lk   = (l >> 4) * 8;

  const int am = m0 + srow;
  const bool aok = am < M;
  const size_t arow = (size_t)am * K;
  const size_t brow = (size_t)(n0 + srow) * K;

  f32x4 acc[4][4];
#pragma unroll
  for (int i = 0; i < 4; ++i)
#pragma unroll
    for (int j = 0; j < 4; ++j) acc[i][j] = (f32x4)0.f;

  short8 ar0, ar1, br0, br1;

  auto LOAD = [&](int k0) {
    if constexpr (ABF) {
      if (aok) {
        ar0 = *reinterpret_cast<const short8*>(&Ab[arow + k0 + sseg]);
        ar1 = *reinterpret_cast<const short8*>(&Ab[arow + k0 + sseg + 8]);
      } else {
        ar0 = (short8)(short)0; ar1 = (short8)(short)0;
      }
    } else {
      if (aok) {
        float f[16];
#pragma unroll
        for (int j = 0; j < 4; ++j) {
          const float4 av =
              *reinterpret_cast<const float4*>(&Af[arow + k0 + sseg + 4 * j]);
          f[4 * j + 0] = av.x; f[4 * j + 1] = av.y;
          f[4 * j + 2] = av.z; f[4 * j + 3] = av.w;
        }
        if constexpr (ADD2) {
#pragma unroll
          for (int j = 0; j < 4; ++j) {
            const float4 av =
                *reinterpret_cast<const float4*>(&A2[arow + k0 + sseg + 4 * j]);
            f[4 * j + 0] += av.x; f[4 * j + 1] += av.y;
            f[4 * j + 2] += av.z; f[4 * j + 3] += av.w;
          }
        }
        alignas(16) unsigned short u[16];
#pragma unroll
        for (int j = 0; j < 16; ++j) u[j] = f2bf(f[j]);
        ar0 = *reinterpret_cast<short8*>(&u[0]);
        ar1 = *reinterpret_cast<short8*>(&u[8]);
      } else {
        ar0 = (short8)(short)0; ar1 = (short8)(short)0;
      }
    }
    br0 = *reinterpret_cast<const short8*>(&Wbf[brow + k0 + sseg]);
    br1 = *reinterpret_cast<const short8*>(&Wbf[brow + k0 + sseg + 8]);
  };

  const int nt = K >> 5;
  LOAD(0);
  for (int tt = 0; tt < nt; ++tt) {
    const int cur = tt & 1;
    *reinterpret_cast<short8*>(&As[cur][srow][sseg])     = ar0;
    *reinterpret_cast<short8*>(&As[cur][srow][sseg + 8]) = ar1;
    *reinterpret_cast<short8*>(&Bs[cur][srow][sseg])     = br0;
    *reinterpret_cast<short8*>(&Bs[cur][srow][sseg + 8]) = br1;
    if (tt + 1 < nt) LOAD((tt + 1) << 5);
    __syncthreads();

    short8 af[4], bfr[4];
#pragma unroll
    for (int fi = 0; fi < 4; ++fi)
      af[fi] = *reinterpret_cast<const short8*>(&As[cur][wm + fi * 16 + lr][lk]);
#pragma unroll
    for (int fj = 0; fj < 4; ++fj)
      bfr[fj] = *reinterpret_cast<const short8*>(&Bs[cur][wn + fj * 16 + lr][lk]);

#pragma unroll
    for (int fi = 0; fi < 4; ++fi)
#pragma unroll
      for (int fj = 0; fj < 4; ++fj)
        acc[fi][fj] = __builtin_amdgcn_mfma_f32_16x16x32_bf16(
            af[fi], bfr[fj], acc[fi][fj], 0, 0, 0);
  }

  const int orow = (l >> 4) * 4;
#pragma unroll
  for (int fi = 0; fi < 4; ++fi) {
#pragma unroll
    for (int fj = 0; fj < 4; ++fj) {
      const int n = n0 + wn + fj * 16 + lr;
      const float bn = bias[n];
#pragma unroll
      for (int i = 0; i < 4; ++i) {
        const int m = m0 + wm + fi * 16 + orow + i;
        if (m < M) {
          float vv = acc[fi][fj][i] + bn;
          if (RELU) vv = fmaxf(vv, 0.f);
          if (OUTBF)
            Cb[(size_t)m * N + n] = f2bf(vv);
          else
            Cf[(size_t)m * N + n] = vv;
        }
      }
    }
  }
}

// ---------------------------------------------------------------------------
// B-resident MFMA GEMM, K=256 fixed (small-M grids). BM=64, BN=128, 4 waves.
// ADD2 applies only for column blocks with n0 < add_nlim (block-uniform).
// ---------------------------------------------------------------------------
template <bool ABF, bool ADD2, bool RELU, bool OUTBF>
__global__ __launch_bounds__(256) void gemm_bres(
    const void* __restrict__ Ap, const float* __restrict__ A2,
    const unsigned short* __restrict__ Wbf, const float* __restrict__ bias,
    void* __restrict__ Cp, int M, int N, int add_nlim) {
  __shared__ unsigned short Bs[32768];        // 64 KB
  __shared__ unsigned short As[2][64][40];    // 10 KB

  const float* Af = (const float*)Ap;
  const unsigned short* Ab = (const unsigned short*)Ap;
  float* Cf = (float*)Cp;
  unsigned short* Cb = (unsigned short*)Cp;

  const int t    = threadIdx.x;
  const int wave = t >> 6;
  const int l    = t & 63;
  const int n0   = blockIdx.x * 128;
  const int m0   = blockIdx.y * 64;
  const int wm   = (wave >> 1) * 32;
  const int wcg  = (wave & 1) * 4;
  const int lr   = l & 15;
  const int lk8  = (l >> 4) * 8;
  const bool doadd = ADD2 && (n0 < add_nlim);

#pragma unroll
  for (int i = 0; i < 16; ++i) {
    const int e  = i * 256 + t;
    const int el = e & 63;
    const int cg = (e >> 6) & 7;
    const int st = e >> 9;
    const int row = n0 + cg * 16 + (el & 15);
    const int col = st * 32 + ((el >> 4) * 8);
    *reinterpret_cast<short8*>(&Bs[e * 8]) =
        *reinterpret_cast<const short8*>(&Wbf[(size_t)row * 256 + col]);
  }

  const int arow = t >> 2;
  const int acol = (t & 3) * 8;
  const int am   = m0 + arow;
  const bool aok = am < M;
  const size_t abase = (size_t)am * 256 + acol;

  float  fr[3][8];
  short8 br_[3];

  auto ALOAD = [&](int slot, int tt) {
    const int k0 = tt * 32;
    if constexpr (ABF) {
      br_[slot] = aok ? *reinterpret_cast<const short8*>(&Ab[abase + k0])
                      : (short8)(short)0;
    } else {
      if (aok) {
        const float4 a0 = *reinterpret_cast<const float4*>(&Af[abase + k0]);
        const float4 a1 = *reinterpret_cast<const float4*>(&Af[abase + k0 + 4]);
        fr[slot][0] = a0.x; fr[slot][1] = a0.y;
        fr[slot][2] = a0.z; fr[slot][3] = a0.w;
        fr[slot][4] = a1.x; fr[slot][5] = a1.y;
        fr[slot][6] = a1.z; fr[slot][7] = a1.w;
        if constexpr (ADD2) {
          if (doadd) {
            const float4 b0 = *reinterpret_cast<const float4*>(&A2[abase + k0]);
            const float4 b1 = *reinterpret_cast<const float4*>(&A2[abase + k0 + 4]);
            fr[slot][0] += b0.x; fr[slot][1] += b0.y;
            fr[slot][2] += b0.z; fr[slot][3] += b0.w;
            fr[slot][4] += b1.x; fr[slot][5] += b1.y;
            fr[slot][6] += b1.z; fr[slot][7] += b1.w;
          }
        }
      } else {
#pragma unroll
        for (int j = 0; j < 8; ++j) fr[slot][j] = 0.f;
      }
    }
  };
  auto AWRITE = [&](int slot, int tt) {
    if constexpr (ABF) {
      *reinterpret_cast<short8*>(&As[tt & 1][arow][acol]) = br_[slot];
    } else {
      alignas(16) unsigned short u[8];
#pragma unroll
      for (int j = 0; j < 8; ++j) u[j] = f2bf(fr[slot][j]);
      *reinterpret_cast<short8*>(&As[tt & 1][arow][acol]) =
          *reinterpret_cast<short8*>(&u[0]);
    }
  };

  f32x4 acc[2][4];
#pragma unroll
  for (int fi = 0; fi < 2; ++fi)
#pragma unroll
    for (int fj = 0; fj < 4; ++fj) acc[fi][fj] = (f32x4)0.f;

  ALOAD(0, 0); ALOAD(1, 1); ALOAD(2, 2);

#pragma unroll
  for (int tt = 0; tt < 8; ++tt) {
    AWRITE(tt % 3, tt);
    if (tt + 3 < 8) ALOAD(tt % 3, tt + 3);
    __syncthreads();

    short8 afr[2];
#pragma unroll
    for (int fi = 0; fi < 2; ++fi)
      afr[fi] = *reinterpret_cast<const short8*>(&As[tt & 1][wm + fi * 16 + lr][lk8]);

#pragma unroll
    for (int fj = 0; fj < 4; ++fj) {
      const short8 bfr = *reinterpret_cast<const short8*>(
          &Bs[(((tt * 8) + wcg + fj) * 64 + l) * 8]);
      acc[0][fj] = __builtin_amdgcn_mfma_f32_16x16x32_bf16(afr[0], bfr, acc[0][fj], 0, 0, 0);
      acc[1][fj] = __builtin_amdgcn_mfma_f32_16x16x32_bf16(afr[1], bfr, acc[1][fj], 0, 0, 0);
    }
  }

  const int or4 = (l >> 4) * 4;
#pragma unroll
  for (int fi = 0; fi < 2; ++fi) {
#pragma unroll
    for (int fj = 0; fj < 4; ++fj) {
      const int n = n0 + (wave & 1) * 64 + fj * 16 + lr;
      const float bn = bias[n];
#pragma unroll
      for (int i = 0; i < 4; ++i) {
        const int m = m0 + wm + fi * 16 + or4 + i;
        if (m < M) {
          float vv = acc[fi][fj][i] + bn;
          if (RELU) vv = fmaxf(vv, 0.f);
          if (OUTBF)
            Cb[(size_t)m * N + n] = f2bf(vv);
          else
            Cf[(size_t)m * N + n] = vv;
        }
      }
    }
  }
}

// ---------------------------------------------------------------------------
// ffn2 split-K: partial[z][M][256] = h1[:, z*256:+256] @ W2[:, same]^T.
// ---------------------------------------------------------------------------
__global__ __launch_bounds__(256) void gemm_ffn2(
    const unsigned short* __restrict__ Ab,
    const unsigned short* __restrict__ Wbf,
    float* __restrict__ Cpart, int M) {
  __shared__ unsigned short Bs[32768];
  __shared__ unsigned short As[2][64][40];

  const int t    = threadIdx.x;
  const int wave = t >> 6;
  const int l    = t & 63;
  const int n0   = blockIdx.x * 128;
  const int m0   = blockIdx.y * 64;
  const int kz   = blockIdx.z * 256;
  const int wm   = (wave >> 1) * 32;
  const int wcg  = (wave & 1) * 4;
  const int lr   = l & 15;
  const int lk8  = (l >> 4) * 8;

#pragma unroll
  for (int i = 0; i < 16; ++i) {
    const int e  = i * 256 + t;
    const int el = e & 63;
    const int cg = (e >> 6) & 7;
    const int st = e >> 9;
    const int row = n0 + cg * 16 + (el & 15);
    const int col = kz + st * 32 + ((el >> 4) * 8);
    *reinterpret_cast<short8*>(&Bs[e * 8]) =
        *reinterpret_cast<const short8*>(&Wbf[(size_t)row * 1024 + col]);
  }

  const int arow = t >> 2;
  const int acol = (t & 3) * 8;
  const int am   = m0 + arow;
  const bool aok = am < M;
  const size_t abase = (size_t)am * 1024 + kz + acol;

  short8 br_[3];
  auto ALOAD = [&](int slot, int tt) {
    br_[slot] = aok ? *reinterpret_cast<const short8*>(&Ab[abase + tt * 32])
                    : (short8)(short)0;
  };
  auto AWRITE = [&](int slot, int tt) {
    *reinterpret_cast<short8*>(&As[tt & 1][arow][acol]) = br_[slot];
  };

  f32x4 acc[2][4];
#pragma unroll
  for (int fi = 0; fi < 2; ++fi)
#pragma unroll
    for (int fj = 0; fj < 4; ++fj) acc[fi][fj] = (f32x4)0.f;

  ALOAD(0, 0); ALOAD(1, 1); ALOAD(2, 2);

#pragma unroll
  for (int tt = 0; tt < 8; ++tt) {
    AWRITE(tt % 3, tt);
    if (tt + 3 < 8) ALOAD(tt % 3, tt + 3);
    __syncthreads();

    short8 afr[2];
#pragma unroll
    for (int fi = 0; fi < 2; ++fi)
      afr[fi] = *reinterpret_cast<const short8*>(&As[tt & 1][wm + fi * 16 + lr][lk8]);

#pragma unroll
    for (int fj = 0; fj < 4; ++fj) {
      const short8 bfr = *reinterpret_cast<const short8*>(
          &Bs[(((tt * 8) + wcg + fj) * 64 + l) * 8]);
      acc[0][fj] = __builtin_amdgcn_mfma_f32_16x16x32_bf16(afr[0], bfr, acc[0][fj], 0, 0, 0);
      acc[1][fj] = __builtin_amdgcn_mfma_f32_16x16x32_bf16(afr[1], bfr, acc[1][fj], 0, 0, 0);
    }
  }

  float* out = &Cpart[(size_t)blockIdx.z * M * 256];
  const int or4 = (l >> 4) * 4;
#pragma unroll
  for (int fi = 0; fi < 2; ++fi) {
#pragma unroll
    for (int fj = 0; fj < 4; ++fj) {
      const int n = n0 + (wave & 1) * 64 + fj * 16 + lr;
#pragma unroll
      for (int i = 0; i < 4; ++i) {
        const int m = m0 + wm + fi * 16 + or4 + i;
        if (m < M) out[(size_t)m * 256 + n] = acc[fi][fj][i];
      }
    }
  }
}

// ---------------------------------------------------------------------------
// Deformable sampling. 2 queries per block, paired-channel uint gathers,
// XCD-chunked block swizzle (1800 % 8 == 0 -> bijective).
// ---------------------------------------------------------------------------
__global__ __launch_bounds__(256) void deform(const float* __restrict__ refp,
                                              const float* __restrict__ offlog,
                                              const unsigned short* __restrict__ v,
                                              unsigned int* __restrict__ accb2) {
  __shared__ float aw[2][128];
  const int nwg  = gridDim.x;
  const int cpx  = nwg >> 3;
  const int bidx = (blockIdx.x % 8) * cpx + blockIdx.x / 8;
  const int t  = threadIdx.x;
  const int tq = t >> 7;
  const int tt = t & 127;
  const int bq = bidx * 2 + tq;
  const int b  = bq / NQ_;
  const int h  = tt >> 4;
  const int dd = tt & 15;

  aw[tq][tt] = offlog[(size_t)bq * 384 + 256 + tt];
  __syncthreads();
  if (t < 16) {
    const int q = t >> 3, hh = t & 7;
    float* a = &aw[q][hh * 16];
    float mx = -1e30f;
#pragma unroll
    for (int i = 0; i < 16; ++i) mx = fmaxf(mx, a[i]);
    float e[16], s = 0.f;
#pragma unroll
    for (int i = 0; i < 16; ++i) { e[i] = expf(a[i] - mx); s += e[i]; }
    const float inv = 1.f / s;
#pragma unroll
    for (int i = 0; i < 16; ++i) a[i] = e[i] * inv;
  }
  __syncthreads();

  constexpr int ST[4] = {0, 16000, 20000, 21000};
  constexpr int HL[4] = {100, 50, 25, 13};
  constexpr int WL[4] = {160, 80, 40, 20};

  float a0 = 0.f, a1 = 0.f;
#pragma unroll
  for (int l = 0; l < L_; ++l) {
    const float rx = refp[(bq * L_ + l) * 2 + 0];
    const float ry = refp[(bq * L_ + l) * 2 + 1];
    const float Wf = (float)WL[l], Hf = (float)HL[l];
    const int   Wi = WL[l], Hi = HL[l];
    const size_t vbase = (size_t)(b * NV_ + ST[l]) * D_ + h * DH + dd * 2;
#pragma unroll
    for (int p = 0; p < P_; ++p) {
      const float ox = offlog[(size_t)bq * 384 + h * 32 + l * 8 + p * 2 + 0];
      const float oy = offlog[(size_t)bq * 384 + h * 32 + l * 8 + p * 2 + 1];
      const float locx = rx + ox / Wf;
      const float locy = ry + oy / Hf;
      const float xl = locx * Wf - 0.5f;
      const float yl = locy * Hf - 0.5f;
      const float x0 = floorf(xl), y0 = floorf(yl);
      const float wx = xl - x0, wy = yl - y0;
      const int x0i = (int)x0, y0i = (int)y0;
      const float w = aw[tq][h * 16 + l * 4 + p];

      float s0 = 0.f, s1 = 0.f;
#pragma unroll
      for (int c = 0; c < 4; ++c) {
        const int xi = x0i + (c & 1);
        const int yi = y0i + (c >> 1);
        const float cw = ((c & 1) ? wx : 1.f - wx) * ((c >> 1) ? wy : 1.f - wy);
        const bool valid = (xi >= 0) && (xi < Wi) && (yi >= 0) && (yi < Hi);
        const int xc = min(max(xi, 0), Wi - 1);
        const int yc = min(max(yi, 0), Hi - 1);
        const unsigned int g2 = *reinterpret_cast<const unsigned int*>(
            &v[vbase + (size_t)(yc * Wi + xc) * D_]);
        const float g0 = bf2f((unsigned short)(g2 & 0xffffu));
        const float g1 = bf2f((unsigned short)(g2 >> 16));
        s0 += valid ? g0 * cw : 0.f;
        s1 += valid ? g1 * cw : 0.f;
      }
      a0 += w * s0;
      a1 += w * s1;
    }
  }
  const unsigned int packed =
      (unsigned int)f2bf(a0) | ((unsigned int)f2bf(a1) << 16);
  accb2[((size_t)bq * D_ + h * DH + dd * 2) >> 1] = packed;
}

// ---------------------------------------------------------------------------
// MFMA flash MHA; fused qkvh[MQ][768]. Tile prefetch (T14-lite).
// XCD-chunked swizzle (grid 480 % 8 == 0): q-tiles sharing one (b,h) K/V
// panel land on the same XCD's L2.
// ---------------------------------------------------------------------------
constexpr int TQM  = 64;
constexpr int NQTM = (NQ_ + TQM - 1) / TQM;   // 15

__global__ __launch_bounds__(256) void mha_mfma(
    const unsigned short* __restrict__ qkvh,
    unsigned short* __restrict__ o) {
  __shared__ unsigned short Qs[64][40];
  __shared__ unsigned short Ks[64][40];
  __shared__ unsigned short Vts[32][72];
  __shared__ unsigned short Ps[64][72];

  const int nwg  = gridDim.x;                 // 480, divisible by 8
  const int cpx  = nwg >> 3;
  const int bx   = (blockIdx.x % 8) * cpx + blockIdx.x / 8;
  const int qt = bx % NQTM;
  const int h  = (bx / NQTM) % H_;
  const int b  = bx / (NQTM * H_);
  const int t  = threadIdx.x;
  const int wave = t >> 6;
  const int l    = t & 63;
  const int q0   = qt * TQM;
  const int wrow = wave * 16;
  const int lr   = l & 15;
  const int lkb  = (l >> 4) * 8;

  const int kr = t >> 2, kcb = (t & 3) * 8;
  const int vk = t & 63, vdb = (t >> 6) * 8;

  short8 ku, vu;
  auto LOADKV = [&](int kt) {
    const int k0 = kt * 64;
    const int nk = min(64, NQ_ - k0);
    ku = (kr < nk) ? *reinterpret_cast<const short8*>(
                         &qkvh[(size_t)(b * NQ_ + k0 + kr) * 768 + 256 + h * DH + kcb])
                   : (short8)(short)0;
    vu = (vk < nk) ? *reinterpret_cast<const short8*>(
                         &qkvh[(size_t)(b * NQ_ + k0 + vk) * 768 + 512 + h * DH + vdb])
                   : (short8)(short)0;
  };

  {
    short8 u;
    if (q0 + kr < NQ_)
      u = *reinterpret_cast<const short8*>(
          &qkvh[(size_t)(b * NQ_ + q0 + kr) * 768 + h * DH + kcb]);
    else
      u = (short8)(short)0;
    *reinterpret_cast<short8*>(&Qs[kr][kcb]) = u;
  }
  LOADKV(0);
  __syncthreads();

  const short8 qa = *reinterpret_cast<const short8*>(&Qs[wrow + lr][lkb]);

  f32x4 oacc[2];
  oacc[0] = (f32x4)0.f; oacc[1] = (f32x4)0.f;
  float m_[4] = {-1e30f, -1e30f, -1e30f, -1e30f};
  float l_[4] = {0.f, 0.f, 0.f, 0.f};

  for (int kt = 0; kt < NQTM; ++kt) {
    const int k0 = kt * 64;
    const int nk = min(64, NQ_ - k0);
    __syncthreads();

    *reinterpret_cast<short8*>(&Ks[kr][kcb]) = ku;
#pragma unroll
    for (int j = 0; j < 8; ++j) Vts[vdb + j][vk] = (unsigned short)vu[j];

    if (kt + 1 < NQTM) LOADKV(kt + 1);
    __syncthreads();

    f32x4 sacc[4];
#pragma unroll
    for (int fj = 0; fj < 4; ++fj)
      sacc[fj] = __builtin_amdgcn_mfma_f32_16x16x32_bf16(
          qa, *reinterpret_cast<const short8*>(&Ks[16 * fj + lr][lkb]),
          (f32x4)0.f, 0, 0, 0);

    bool cv[4];
#pragma unroll
    for (int fj = 0; fj < 4; ++fj) cv[fj] = (16 * fj + lr) < nk;

    float p0[4], p1[4], p2[4], p3[4], sc_[4];
#pragma unroll
    for (int i = 0; i < 4; ++i) {
      float tm = -1e30f;
      if (cv[0]) tm = fmaxf(tm, sacc[0][i]);
      if (cv[1]) tm = fmaxf(tm, sacc[1][i]);
      if (cv[2]) tm = fmaxf(tm, sacc[2][i]);
      if (cv[3]) tm = fmaxf(tm, sacc[3][i]);
      tm = fmaxf(tm, __shfl_xor(tm, 1));
      tm = fmaxf(tm, __shfl_xor(tm, 2));
      tm = fmaxf(tm, __shfl_xor(tm, 4));
      tm = fmaxf(tm, __shfl_xor(tm, 8));
      const float mn = fmaxf(m_[i], tm);
      sc_[i] = __expf(m_[i] - mn);
      m_[i] = mn;
      const float e0 = cv[0] ? __expf(sacc[0][i] - mn) : 0.f;
      const float e1 = cv[1] ? __expf(sacc[1][i] - mn) : 0.f;
      const float e2 = cv[2] ? __expf(sacc[2][i] - mn) : 0.f;
      const float e3 = cv[3] ? __expf(sacc[3][i] - mn) : 0.f;
      p0[i] = e0; p1[i] = e1; p2[i] = e2; p3[i] = e3;
      float rs = e0 + e1 + e2 + e3;
      rs += __shfl_xor(rs, 1);
      rs += __shfl_xor(rs, 2);
      rs += __shfl_xor(rs, 4);
      rs += __shfl_xor(rs, 8);
      l_[i] = l_[i] * sc_[i] + rs;
    }

#pragma unroll
    for (int i = 0; i < 4; ++i) {
      const int pr = wrow + (l >> 4) * 4 + i;
      Ps[pr][0  + lr] = f2bf(p0[i]);
      Ps[pr][16 + lr] = f2bf(p1[i]);
      Ps[pr][32 + lr] = f2bf(p2[i]);
      Ps[pr][48 + lr] = f2bf(p3[i]);
    }

    const short8 pa0 = *reinterpret_cast<const short8*>(&Ps[wrow + lr][lkb]);
    const short8 pa1 = *reinterpret_cast<const short8*>(&Ps[wrow + lr][lkb + 32]);
#pragma unroll
    for (int nt = 0; nt < 2; ++nt) {
      f32x4 c = oacc[nt];
#pragma unroll
      for (int i = 0; i < 4; ++i) c[i] *= sc_[i];
      c = __builtin_amdgcn_mfma_f32_16x16x32_bf16(
          pa0, *reinterpret_cast<const short8*>(&Vts[16 * nt + lr][lkb]), c, 0, 0, 0);
      c = __builtin_amdgcn_mfma_f32_16x16x32_bf16(
          pa1, *reinterpret_cast<const short8*>(&Vts[16 * nt + lr][lkb + 32]), c, 0, 0, 0);
      oacc[nt] = c;
    }
  }

#pragma unroll
  for (int i = 0; i < 4; ++i) {
    const int r = (l >> 4) * 4 + i;
    const int q = q0 + wrow + r;
    if (q < NQ_) {
      const float inv = 1.f / l_[i];
      o[(size_t)(b * NQ_ + q) * D_ + h * DH + 0  + lr] = f2bf(oacc[0][i] * inv);
      o[(size_t)(b * NQ_ + q) * D_ + h * DH + 16 + lr] = f2bf(oacc[1][i] * inv);
    }
  }
}

// ---------------------------------------------------------------------------
// out = LayerNorm(res + add) * g + b — one wave per row, shfl reductions.
// ---------------------------------------------------------------------------
__global__ __launch_bounds__(256) void ln4(const float* __restrict__ res,
                                           const float* __restrict__ add,
                                           const float* __restrict__ g,
                                           const float* __restrict__ bt,
                                           float* __restrict__ out) {
  const int wave = threadIdx.x >> 6, lane = threadIdx.x & 63;
  const int r = blockIdx.x * 4 + wave;
  const size_t base = (size_t)r * D_ + lane * 4;
  const float4 a = *reinterpret_cast<const float4*>(&res[base]);
  const float4 bv = *reinterpret_cast<const float4*>(&add[base]);
  float4 x;
  x.x = a.x + bv.x; x.y = a.y + bv.y; x.z = a.z + bv.z; x.w = a.w + bv.w;

  float s = x.x + x.y + x.z + x.w;
#pragma unroll
  for (int off = 1; off < 64; off <<= 1) s += __shfl_xor(s, off);
  const float mean = s * (1.f / D_);

  const float dx0 = x.x - mean, dx1 = x.y - mean, dx2 = x.z - mean,
              dx3 = x.w - mean;
  float v = dx0 * dx0 + dx1 * dx1 + dx2 * dx2 + dx3 * dx3;
#pragma unroll
  for (int off = 1; off < 64; off <<= 1) v += __shfl_xor(v, off);
  const float rstd = rsqrtf(v * (1.f / D_) + 1e-5f);

  const float4 gg = *reinterpret_cast<const float4*>(&g[lane * 4]);
  const float4 bb = *reinterpret_cast<const float4*>(&bt[lane * 4]);
  float4 o;
  o.x = dx0 * rstd * gg.x + bb.x;
  o.y = dx1 * rstd * gg.y + bb.y;
  o.z = dx2 * rstd * gg.z + bb.z;
  o.w = dx3 * rstd * gg.w + bb.w;
  *reinterpret_cast<float4*>(&out[base]) = o;
}

// ---------------------------------------------------------------------------
// Fused ffn2-reduce + LayerNorm: out = LN(res + sum_z part[z] + bias).
// Same arithmetic order as reduce4 followed by ln4.
// ---------------------------------------------------------------------------
__global__ __launch_bounds__(256) void ln4r(const float* __restrict__ res,
                                            const float* __restrict__ part,
                                            const float* __restrict__ bias,
                                            const float* __restrict__ g,
                                            const float* __restrict__ bt,
                                            float* __restrict__ out, int M) {
  const int wave = threadIdx.x >> 6, lane = threadIdx.x & 63;
  const int r = blockIdx.x * 4 + wave;
  const size_t base = (size_t)r * D_ + lane * 4;
  const size_t tot = (size_t)M * 256;

  float4 s = *reinterpret_cast<const float4*>(&part[base]);
  const float4 p1 = *reinterpret_cast<const float4*>(&part[tot + base]);
  const float4 p2 = *reinterpret_cast<const float4*>(&part[2 * tot + base]);
  const float4 p3 = *reinterpret_cast<const float4*>(&part[3 * tot + base]);
  const float4 bb2 = *reinterpret_cast<const float4*>(&bias[lane * 4]);
  s.x += p1.x + p2.x + p3.x + bb2.x;
  s.y += p1.y + p2.y + p3.y + bb2.y;
  s.z += p1.z + p2.z + p3.z + bb2.z;
  s.w += p1.w + p2.w + p3.w + bb2.w;

  const float4 a = *reinterpret_cast<const float4*>(&res[base]);
  float4 x;
  x.x = a.x + s.x; x.y = a.y + s.y; x.z = a.z + s.z; x.w = a.w + s.w;

  float sm = x.x + x.y + x.z + x.w;
#pragma unroll
  for (int off = 1; off < 64; off <<= 1) sm += __shfl_xor(sm, off);
  const float mean = sm * (1.f / D_);

  const float dx0 = x.x - mean, dx1 = x.y - mean, dx2 = x.z - mean,
              dx3 = x.w - mean;
  float v = dx0 * dx0 + dx1 * dx1 + dx2 * dx2 + dx3 * dx3;
#pragma unroll
  for (int off = 1; off < 64; off <<= 1) v += __shfl_xor(v, off);
  const float rstd = rsqrtf(v * (1.f / D_) + 1e-5f);

  const float4 gg = *reinterpret_cast<const float4*>(&g[lane * 4]);
  const float4 bb = *reinterpret_cast<const float4*>(&bt[lane * 4]);
  float4 o;
  o.x = dx0 * rstd * gg.x + bb.x;
  o.y = dx1 * rstd * gg.y + bb.y;
  o.z = dx2 * rstd * gg.z + bb.z;
  o.w = dx3 * rstd * gg.w + bb.w;
  *reinterpret_cast<float4*>(&out[base]) = o;
}

// ---------------------------------------------------------------------------
extern "C" void kernel_launch(void* const* d_in, const int* in_sizes, int n_in,
                              void* d_out, int out_size, void* d_ws,
                              size_t ws_size, hipStream_t stream) {
  const float* tgt   = (const float*)d_in[0];
  const float* pos   = (const float*)d_in[1];
  const float* refp  = (const float*)d_in[2];
  const float* mem   = (const float*)d_in[3];
  const float* Wv    = (const float*)d_in[4];
  const float* bv    = (const float*)d_in[5];
  const float* Wo    = (const float*)d_in[6];
  const float* bo    = (const float*)d_in[7];
  const float* Wa    = (const float*)d_in[8];
  const float* ba    = (const float*)d_in[9];
  const float* Wca   = (const float*)d_in[10];
  const float* bca   = (const float*)d_in[11];
  const float* g1    = (const float*)d_in[12];
  const float* b1    = (const float*)d_in[13];
  const float* Win   = (const float*)d_in[14];
  const float* bin   = (const float*)d_in[15];
  const float* Wsa   = (const float*)d_in[16];
  const float* bsa   = (const float*)d_in[17];
  const float* g2    = (const float*)d_in[18];
  const float* b2    = (const float*)d_in[19];
  const float* W1    = (const float*)d_in[20];
  const float* bb1   = (const float*)d_in[21];
  const float* W2    = (const float*)d_in[22];
  const float* bb2   = (const float*)d_in[23];
  const float* g3    = (const float*)d_in[24];
  const float* b3    = (const float*)d_in[25];

  char* cur = (char*)d_ws;
  auto alloc = [&](size_t bytes) {
    char* p = cur;
    cur += (bytes + 255) & ~(size_t)255;
    return (void*)p;
  };
  unsigned short* v_bf    = (unsigned short*)alloc((size_t)MV * 256 * 2);
  float*          offlog  = (float*)alloc((size_t)MQ * 384 * 4);
  unsigned short* accb_bf = (unsigned short*)alloc((size_t)MQ * 256 * 2);
  float*          tmp     = (float*)alloc((size_t)MQ * 256 * 4);
  float*          x1      = (float*)alloc((size_t)MQ * 256 * 4);
  float*          x2      = (float*)alloc((size_t)MQ * 256 * 4);
  unsigned short* qkvh_bf = (unsigned short*)alloc((size_t)MQ * 768 * 2);
  unsigned short* obuf_bf = (unsigned short*)alloc((size_t)MQ * 256 * 2);
  unsigned short* h1_bf   = (unsigned short*)alloc((size_t)MQ * 1024 * 2);
  float*          part    = (float*)alloc((size_t)4 * MQ * 256 * 4);
  unsigned short* Wv_bf   = (unsigned short*)alloc(65536 * 2);
  unsigned short* Wfu_bf  = (unsigned short*)alloc(98304 * 2);   // [Wo|Wa]
  unsigned short* Wca_bf  = (unsigned short*)alloc(65536 * 2);
  unsigned short* Win_bf  = (unsigned short*)alloc(196608 * 2);
  unsigned short* Wsa_bf  = (unsigned short*)alloc(65536 * 2);
  unsigned short* W1_bf   = (unsigned short*)alloc(262144 * 2);
  unsigned short* W2_bf   = (unsigned short*)alloc(262144 * 2);
  float*          biasqkv = (float*)alloc(768 * 4);
  float*          bfused  = (float*)alloc(384 * 4);

  const float qscale = 0.17677669529663687f;  // 1/sqrt(32)

  CvtArgs ca;
  ca.src[0] = Wv;            ca.dst[0] = Wv_bf;          ca.n[0] = 65536;  ca.scl[0] = 1.f;
  ca.src[1] = Wo;            ca.dst[1] = Wfu_bf;         ca.n[1] = 65536;  ca.scl[1] = 1.f;
  ca.src[2] = Wa;            ca.dst[2] = Wfu_bf + 65536; ca.n[2] = 32768;  ca.scl[2] = 1.f;
  ca.src[3] = Wca;           ca.dst[3] = Wca_bf;         ca.n[3] = 65536;  ca.scl[3] = 1.f;
  ca.src[4] = Win;           ca.dst[4] = Win_bf;         ca.n[4] = 65536;  ca.scl[4] = qscale;
  ca.src[5] = Win + 65536;   ca.dst[5] = Win_bf + 65536; ca.n[5] = 131072; ca.scl[5] = 1.f;
  ca.src[6] = Wsa;           ca.dst[6] = Wsa_bf;         ca.n[6] = 65536;  ca.scl[6] = 1.f;
  ca.src[7] = W1;            ca.dst[7] = W1_bf;          ca.n[7] = 262144; ca.scl[7] = 1.f;
  ca.src[8] = W2;            ca.dst[8] = W2_bf;          ca.n[8] = 262144; ca.scl[8] = 1.f;
  cvtw<<<dim3(64, 9), 256, 0, stream>>>(ca);
  biasprep<<<1, 768, 0, stream>>>(bin, bo, ba, biasqkv, bfused);

  const int mqb64  = (MQ + 63) / 64;    // 57
  const int mvb128 = (MV + 127) / 128;  // 665

  // value projection -> bf16 (best-measured: depth-1 double-buffer 128x128)
  gemm_db<false, false, false, true><<<dim3(2, mvb128), 256, 0, stream>>>(
      mem, nullptr, Wv_bf, bv, v_bf, MV, 256, 256);
  // (tgt+pos) @ [Wo|Wa] -> offlog f32  (small-M: B-resident)
  gemm_bres<false, true, false, false><<<dim3(3, mqb64), 256, 0, stream>>>(
      tgt, pos, Wfu_bf, bfused, offlog, MQ, 384, 384);
  deform<<<MQ / 2, 256, 0, stream>>>(refp, offlog, v_bf,
                                     (unsigned int*)accb_bf);
  gemm_bres<true, false, false, false><<<dim3(2, mqb64), 256, 0, stream>>>(
      accb_bf, nullptr, Wca_bf, bca, tmp, MQ, 256, 0);
  ln4<<<MQ / 4, 256, 0, stream>>>(tgt, tmp, g1, b1, x1);
  // fused QKV: cols <512 use A=x1+pos (Q pre-scaled in weights/bias), V uses x1
  gemm_bres<false, true, false, true><<<dim3(6, mqb64), 256, 0, stream>>>(
      x1, pos, Win_bf, biasqkv, qkvh_bf, MQ, 768, 512);
  mha_mfma<<<B_ * H_ * NQTM, 256, 0, stream>>>(qkvh_bf, obuf_bf);
  gemm_bres<true, false, false, false><<<dim3(2, mqb64), 256, 0, stream>>>(
      obuf_bf, nullptr, Wsa_bf, bsa, tmp, MQ, 256, 0);
  ln4<<<MQ / 4, 256, 0, stream>>>(x1, tmp, g2, b2, x2);
  gemm_bres<false, false, true, true><<<dim3(8, mqb64), 256, 0, stream>>>(
      x2, nullptr, W1_bf, bb1, h1_bf, MQ, 1024, 0);
  // ffn2: split-K x4; reduce + bias + LN fused into ln4r
  gemm_ffn2<<<dim3(2, mqb64, 4), 256, 0, stream>>>(h1_bf, W2_bf, part, MQ);
  ln4r<<<MQ / 4, 256, 0, stream>>>(x2, part, bb2, g3, b3, (float*)d_out, MQ);
}